// Round 1
// baseline (590.517 us; speedup 1.0000x reference)
//
#include <hip/hip_runtime.h>

// ---------------- problem constants ----------------
constexpr int B = 8, H = 100, W = 100, A = 9, G = 50, K = 18;
constexpr int NPROP = B * H * W * A;   // 720000 proposal boxes
constexpr int NPOS  = B * H * W;       // 80000 spatial positions
constexpr int CAND_CAP = 65536;        // IoU>0.7 candidates (realistically ~50-500)
constexpr float THR = 0.7f;

// JAX PRNG mode: 1 = threefry_partitionable (modern JAX default), 0 = legacy
#define JAX_PARTITIONABLE 1

// ---------------- static device state (re-inited every launch) ----------------
__device__ unsigned int g_posmax[NPOS];            // per-position max IoU (float bits)
__device__ int g_candCount;
__device__ unsigned long long g_cand[CAND_CAP];    // key = (iou_bits<<32) | ~flat_idx

// ---------------- threefry2x32 (JAX-exact, 20 rounds) ----------------
__device__ __forceinline__ unsigned int rotl32(unsigned int x, int r) {
    return (x << r) | (x >> (32 - r));
}
__device__ __forceinline__ void tfr(unsigned int& x0, unsigned int& x1, int r) {
    x0 += x1; x1 = rotl32(x1, r); x1 ^= x0;
}
__device__ void threefry2x32(unsigned int k0, unsigned int k1,
                             unsigned int c0, unsigned int c1,
                             unsigned int& o0, unsigned int& o1) {
    unsigned int ks2 = k0 ^ k1 ^ 0x1BD11BDAu;
    unsigned int x0 = c0 + k0, x1 = c1 + k1;
    tfr(x0,x1,13); tfr(x0,x1,15); tfr(x0,x1,26); tfr(x0,x1, 6);
    x0 += k1;  x1 += ks2 + 1u;
    tfr(x0,x1,17); tfr(x0,x1,29); tfr(x0,x1,16); tfr(x0,x1,24);
    x0 += ks2; x1 += k0 + 2u;
    tfr(x0,x1,13); tfr(x0,x1,15); tfr(x0,x1,26); tfr(x0,x1, 6);
    x0 += k0;  x1 += k1 + 3u;
    tfr(x0,x1,17); tfr(x0,x1,29); tfr(x0,x1,16); tfr(x0,x1,24);
    x0 += k1;  x1 += ks2 + 4u;
    tfr(x0,x1,13); tfr(x0,x1,15); tfr(x0,x1,26); tfr(x0,x1, 6);
    x0 += ks2; x1 += k0 + 5u;
    o0 = x0; o1 = x1;
}

// key(42) = (0,42); split -> kp, kn
__device__ void derive_keys(unsigned int& kp0, unsigned int& kp1,
                            unsigned int& kn0, unsigned int& kn1) {
#if JAX_PARTITIONABLE
    // fold-like split: key_i = full output of enc(counter=i)
    threefry2x32(0u, 42u, 0u, 0u, kp0, kp1);
    threefry2x32(0u, 42u, 0u, 1u, kn0, kn1);
#else
    // original split: counts [0,1,2,3] -> pairs (0,2),(1,3); reshape(2,2)
    unsigned int a0, b0, a1, b1;
    threefry2x32(0u, 42u, 0u, 2u, a0, b0);
    threefry2x32(0u, 42u, 1u, 3u, a1, b1);
    kp0 = a0; kp1 = a1; kn0 = b0; kn1 = b1;
#endif
}

// jax.random.uniform(key, (n,))[i], float32 in [0,1)
__device__ float jax_uniform(unsigned int k0, unsigned int k1, unsigned int i, unsigned int n) {
    unsigned int bits;
#if JAX_PARTITIONABLE
    unsigned int o0, o1;
    threefry2x32(k0, k1, 0u, i, o0, o1);   // counter = 64-bit iota (hi=0, lo=i)
    bits = o0 ^ o1;
#else
    unsigned int half = n >> 1;            // n even for both our shapes
    unsigned int o0, o1;
    if (i < half) { threefry2x32(k0, k1, i, i + half, o0, o1); bits = o0; }
    else          { threefry2x32(k0, k1, i - half, i, o0, o1); bits = o1; }
#endif
    unsigned int fb = (bits >> 9) | 0x3F800000u;
    return __uint_as_float(fb) - 1.0f;
}

// ---------------- kernels ----------------
__global__ void init_kernel() {
    int i = blockIdx.x * blockDim.x + threadIdx.x;
    if (i == 0) g_candCount = 0;
    for (int p = i; p < NPOS; p += gridDim.x * blockDim.x) g_posmax[p] = 0u;
}

// One thread per (b,h,w,a): 50 IoUs vs gt boxes. Exact IEEE fp32, no contraction.
__global__ void iou_kernel(const float* __restrict__ proposals,
                           const float* __restrict__ gtp) {
    __shared__ float4 sgt[G];
    __shared__ float  sga[G];
    int t = threadIdx.x;
    if (t < G) {
        float4 gb = reinterpret_cast<const float4*>(gtp)[t];
        sgt[t] = gb;
        sga[t] = __fmul_rn(__fsub_rn(gb.z, gb.x), __fsub_rn(gb.w, gb.y));
    }
    __syncthreads();
    int p = blockIdx.x * blockDim.x + t;
    if (p >= NPROP) return;

    float4 pb = reinterpret_cast<const float4*>(proposals)[p];
    float area_p = __fmul_rn(__fsub_rn(pb.z, pb.x), __fsub_rn(pb.w, pb.y));
    int pos = p / A;
    int a   = p - pos * A;
    int baseIdx = pos * (G * A) + a;   // flat idx of (pos, g=0, a) in (B,H,W,G,A)

    float vmax = 0.0f;
    for (int g = 0; g < G; ++g) {
        float4 gb = sgt[g];
        float ix1 = fmaxf(pb.x, gb.x);
        float iy1 = fmaxf(pb.y, gb.y);
        float ix2 = fminf(pb.z, gb.z);
        float iy2 = fminf(pb.w, gb.w);
        float mx = fmaxf(__fsub_rn(ix2, ix1), 0.0f);
        float my = fmaxf(__fsub_rn(iy2, iy1), 0.0f);
        float inter = __fmul_rn(mx, my);
        // (((area_p + area_g) - inter) + EPS)  — reference association order
        float den = __fadd_rn(__fsub_rn(__fadd_rn(area_p, sga[g]), inter), 1e-8f);
        float iou = __fdiv_rn(inter, den);
        vmax = fmaxf(vmax, iou);
        if (iou > THR) {
            int slot = atomicAdd(&g_candCount, 1);
            if (slot < CAND_CAP) {
                unsigned int idx = (unsigned int)(baseIdx + g * A);
                g_cand[slot] = ((unsigned long long)__float_as_uint(iou) << 32)
                             | (unsigned long long)(~idx);
            }
        }
    }
    atomicMax(&g_posmax[pos], __float_as_uint(vmax));   // iou >= 0 -> uint order == float order
}

#define K2_THREADS 128
// Single block: sort candidates (top-100), threefry scores, top-10, gather positives.
__global__ void pos_kernel(const float* __restrict__ proposals,
                           const float* __restrict__ cls_prob,
                           const float* __restrict__ anchor_prob,
                           const float* __restrict__ gtp,
                           const int*   __restrict__ gtc,
                           float* __restrict__ out) {
    __shared__ unsigned long long red[K2_THREADS];
    __shared__ unsigned long long list[100];
    __shared__ unsigned long long skeys[K2_THREADS];
    __shared__ int selIdx[10];
    int t = threadIdx.x;

    int C = g_candCount;
    if (C > CAND_CAP) C = CAND_CAP;
    int n_list = C < 100 ? C : 100;

    // top-n_list selection (desc by key = value desc, index asc), removal by zeroing
    for (int r = 0; r < n_list; ++r) {
        unsigned long long best = 0ull;
        for (int i = t; i < C; i += K2_THREADS) {
            unsigned long long v = g_cand[i];
            if (v > best) best = v;
        }
        red[t] = best;
        __syncthreads();
        for (int s = K2_THREADS / 2; s > 0; s >>= 1) {
            if (t < s && red[t + s] > red[t]) red[t] = red[t + s];
            __syncthreads();
        }
        unsigned long long win = red[0];
        if (t == 0) list[r] = win;
        for (int i = t; i < C; i += K2_THREADS)
            if (g_cand[i] == win) g_cand[i] = 0ull;
        __syncthreads();
    }

    // scores: all list entries have iou > 0.7 -> mask true -> score = uniform(kp,100)[i]
    unsigned int kp0, kp1, kn0, kn1;
    derive_keys(kp0, kp1, kn0, kn1);
    unsigned long long sk = 0ull;
    if (t < n_list) {
        float u = jax_uniform(kp0, kp1, (unsigned)t, 100u);   // u >= 0
        sk = ((unsigned long long)__float_as_uint(u) << 32) | (unsigned long long)(~(unsigned)t);
    }
    skeys[t] = sk;
    __syncthreads();

    if (t == 0) {
        for (int j = 0; j < 10; ++j) {
            unsigned long long best = 0ull; int bi = 0;
            for (int i = 0; i < n_list; ++i)
                if (skeys[i] > best) { best = skeys[i]; bi = i; }
            selIdx[j] = bi;
            skeys[bi] = 0ull;
        }
    }
    __syncthreads();

    if (t < 10) {
        unsigned long long key = list[selIdx[t]];
        unsigned int fidx = ~(unsigned int)(key & 0xFFFFFFFFull);
        int a = fidx % A; unsigned int rest = fidx / A;
        int g = rest % G; rest /= G;
        int w = rest % W; rest /= W;
        int h = rest % H; int b = rest / H;
        int pos = (b * H + h) * W + w;

        out[t * 5 + 0] = (float)b;
        out[t * 5 + 1] = (float)h;
        out[t * 5 + 2] = (float)w;
        out[t * 5 + 3] = (float)g;
        out[t * 5 + 4] = (float)a;
        const float* pb = proposals + (size_t)(pos * A + a) * 4;
        for (int q = 0; q < 4; ++q) out[50 + t * 4 + q] = pb[q];
        const float* cp = cls_prob + (size_t)pos * K;
        for (int q = 0; q < K; ++q) out[90 + t * K + q] = cp[q];
        const float* gp = gtp + g * 4;
        for (int q = 0; q < 4; ++q) out[270 + t * 4 + q] = gp[q];
        out[310 + t] = (float)gtc[g];
        out[320 + t] = (float)a;
        const float* ap = anchor_prob + (size_t)pos * K;
        for (int q = 0; q < K; ++q) out[330 + t * K + q] = ap[q];
    }
}

#define K3_THREADS 256
// Single block: top-10 uniforms among positions with max IoU < 0.7, gather negatives.
__global__ void neg_kernel(const float* __restrict__ cls_prob, float* __restrict__ out) {
    __shared__ unsigned long long red[K3_THREADS];
    __shared__ unsigned long long swin[10];
    int t = threadIdx.x;

    unsigned int kp0, kp1, kn0, kn1;
    derive_keys(kp0, kp1, kn0, kn1);

    unsigned long long top[10];
#pragma unroll
    for (int j = 0; j < 10; ++j) top[j] = 0ull;

    for (int pos = t; pos < NPOS; pos += K3_THREADS) {
        float m = __uint_as_float(g_posmax[pos]);
        if (m < THR) {
            float u = jax_uniform(kn0, kn1, (unsigned)pos, (unsigned)NPOS);
            unsigned long long key = ((unsigned long long)__float_as_uint(u) << 32)
                                   | (unsigned long long)(~(unsigned)pos);
#pragma unroll
            for (int j = 0; j < 10; ++j) {   // sorted-desc bubble insert (static idx)
                if (key > top[j]) { unsigned long long tmp = top[j]; top[j] = key; key = tmp; }
            }
        }
    }

    for (int r = 0; r < 10; ++r) {
        unsigned long long best = 0ull;
#pragma unroll
        for (int j = 0; j < 10; ++j) if (top[j] > best) best = top[j];
        red[t] = best;
        __syncthreads();
        for (int s = K3_THREADS / 2; s > 0; s >>= 1) {
            if (t < s && red[t + s] > red[t]) red[t] = red[t + s];
            __syncthreads();
        }
        unsigned long long win = red[0];
        if (t == 0) swin[r] = win;
#pragma unroll
        for (int j = 0; j < 10; ++j) if (top[j] == win) top[j] = 0ull;
        __syncthreads();
    }

    if (t < 10) {
        unsigned long long win = swin[t];
        unsigned int pos_ = ~(unsigned int)(win & 0xFFFFFFFFull);
        if (win == 0ull) pos_ = 0;   // defensive, cannot trigger (~79950 masked)
        int nb = pos_ / (H * W);
        int nh = (pos_ / W) % H;
        int nw = pos_ % W;
        out[510 + t * 3 + 0] = (float)nb;
        out[510 + t * 3 + 1] = (float)nh;
        out[510 + t * 3 + 2] = (float)nw;
        const float* cp = cls_prob + (size_t)pos_ * K;
        for (int q = 0; q < K; ++q) out[540 + t * K + q] = cp[q];
    }
}

// ---------------- launcher ----------------
extern "C" void kernel_launch(void* const* d_in, const int* in_sizes, int n_in,
                              void* d_out, int out_size, void* d_ws, size_t ws_size,
                              hipStream_t stream) {
    const float* proposals   = (const float*)d_in[0];
    const float* cls_prob    = (const float*)d_in[1];
    const float* anchor_prob = (const float*)d_in[2];
    const float* gtp         = (const float*)d_in[3];
    const int*   gtc         = (const int*)d_in[4];
    float* out = (float*)d_out;

    init_kernel<<<313, 256, 0, stream>>>();
    iou_kernel<<<(NPROP + 255) / 256, 256, 0, stream>>>(proposals, gtp);
    pos_kernel<<<1, K2_THREADS, 0, stream>>>(proposals, cls_prob, anchor_prob, gtp, gtc, out);
    neg_kernel<<<1, K3_THREADS, 0, stream>>>(cls_prob, out);
}

// Round 2
// 111.762 us; speedup vs baseline: 5.2837x; 5.2837x over previous
//
#include <hip/hip_runtime.h>

// ---------------- problem constants ----------------
constexpr int B = 8, H = 100, W = 100, A = 9, G = 50, K = 18;
constexpr int NPROP = B * H * W * A;   // 720000 proposal boxes
constexpr int NPOS  = B * H * W;       // 80000 spatial positions
constexpr int CAND_CAP = 65536;        // IoU>0.7 candidates
constexpr float THR = 0.7f;

#define JAX_PARTITIONABLE 1
#define NEG_BLOCKS 32
#define NEG_T 256

// ---------------- static device state (re-inited every launch) ----------------
__device__ unsigned int g_posmax[NPOS];            // per-position max IoU (float bits)
__device__ int g_candCount;
__device__ unsigned long long g_cand[CAND_CAP];    // key = (iou_bits<<32) | ~flat_idx

// ---------------- threefry2x32 (JAX-exact, 20 rounds) ----------------
__device__ __forceinline__ unsigned int rotl32(unsigned int x, int r) {
    return (x << r) | (x >> (32 - r));
}
__device__ __forceinline__ void tfr(unsigned int& x0, unsigned int& x1, int r) {
    x0 += x1; x1 = rotl32(x1, r); x1 ^= x0;
}
__device__ void threefry2x32(unsigned int k0, unsigned int k1,
                             unsigned int c0, unsigned int c1,
                             unsigned int& o0, unsigned int& o1) {
    unsigned int ks2 = k0 ^ k1 ^ 0x1BD11BDAu;
    unsigned int x0 = c0 + k0, x1 = c1 + k1;
    tfr(x0,x1,13); tfr(x0,x1,15); tfr(x0,x1,26); tfr(x0,x1, 6);
    x0 += k1;  x1 += ks2 + 1u;
    tfr(x0,x1,17); tfr(x0,x1,29); tfr(x0,x1,16); tfr(x0,x1,24);
    x0 += ks2; x1 += k0 + 2u;
    tfr(x0,x1,13); tfr(x0,x1,15); tfr(x0,x1,26); tfr(x0,x1, 6);
    x0 += k0;  x1 += k1 + 3u;
    tfr(x0,x1,17); tfr(x0,x1,29); tfr(x0,x1,16); tfr(x0,x1,24);
    x0 += k1;  x1 += ks2 + 4u;
    tfr(x0,x1,13); tfr(x0,x1,15); tfr(x0,x1,26); tfr(x0,x1, 6);
    x0 += ks2; x1 += k0 + 5u;
    o0 = x0; o1 = x1;
}

__device__ void derive_keys(unsigned int& kp0, unsigned int& kp1,
                            unsigned int& kn0, unsigned int& kn1) {
#if JAX_PARTITIONABLE
    threefry2x32(0u, 42u, 0u, 0u, kp0, kp1);
    threefry2x32(0u, 42u, 0u, 1u, kn0, kn1);
#else
    unsigned int a0, b0, a1, b1;
    threefry2x32(0u, 42u, 0u, 2u, a0, b0);
    threefry2x32(0u, 42u, 1u, 3u, a1, b1);
    kp0 = a0; kp1 = a1; kn0 = b0; kn1 = b1;
#endif
}

__device__ float jax_uniform(unsigned int k0, unsigned int k1, unsigned int i, unsigned int n) {
    unsigned int bits;
#if JAX_PARTITIONABLE
    unsigned int o0, o1;
    threefry2x32(k0, k1, 0u, i, o0, o1);
    bits = o0 ^ o1;
#else
    unsigned int half = n >> 1;
    unsigned int o0, o1;
    if (i < half) { threefry2x32(k0, k1, i, i + half, o0, o1); bits = o0; }
    else          { threefry2x32(k0, k1, i - half, i, o0, o1); bits = o1; }
#endif
    unsigned int fb = (bits >> 9) | 0x3F800000u;
    return __uint_as_float(fb) - 1.0f;
}

// ---------------- kernels ----------------
__global__ void init_kernel() {
    int i = blockIdx.x * blockDim.x + threadIdx.x;
    if (i == 0) g_candCount = 0;
    for (int p = i; p < NPOS; p += gridDim.x * blockDim.x) g_posmax[p] = 0u;
}

// One thread per (b,h,w,a): 50 IoUs vs gt boxes. Exact IEEE fp32, no contraction.
// Candidate append is wave-aggregated: one atomicAdd per wave per g-iteration.
__global__ void iou_kernel(const float* __restrict__ proposals,
                           const float* __restrict__ gtp) {
    __shared__ float4 sgt[G];
    __shared__ float  sga[G];
    int t = threadIdx.x;
    if (t < G) {
        float4 gb = reinterpret_cast<const float4*>(gtp)[t];
        sgt[t] = gb;
        sga[t] = __fmul_rn(__fsub_rn(gb.z, gb.x), __fsub_rn(gb.w, gb.y));
    }
    __syncthreads();
    int p = blockIdx.x * blockDim.x + t;
    if (p >= NPROP) return;

    float4 pb = reinterpret_cast<const float4*>(proposals)[p];
    float area_p = __fmul_rn(__fsub_rn(pb.z, pb.x), __fsub_rn(pb.w, pb.y));
    int pos = p / A;
    int a   = p - pos * A;
    int baseIdx = pos * (G * A) + a;
    int lane = t & 63;

    float vmax = 0.0f;
    for (int g = 0; g < G; ++g) {
        float4 gb = sgt[g];
        float ix1 = fmaxf(pb.x, gb.x);
        float iy1 = fmaxf(pb.y, gb.y);
        float ix2 = fminf(pb.z, gb.z);
        float iy2 = fminf(pb.w, gb.w);
        float mx = fmaxf(__fsub_rn(ix2, ix1), 0.0f);
        float my = fmaxf(__fsub_rn(iy2, iy1), 0.0f);
        float inter = __fmul_rn(mx, my);
        float den = __fadd_rn(__fsub_rn(__fadd_rn(area_p, sga[g]), inter), 1e-8f);
        float iou = __fdiv_rn(inter, den);
        vmax = fmaxf(vmax, iou);
        bool pred = iou > THR;
        unsigned long long msk = __ballot(pred);
        if (msk != 0ull) {
            int leader = __builtin_ctzll(msk);
            int cnt = __popcll(msk);
            int base = 0;
            if (lane == leader) base = atomicAdd(&g_candCount, cnt);
            base = __shfl(base, leader);
            if (pred) {
                int off = __popcll(msk & ((1ull << lane) - 1ull));
                int slot = base + off;
                if (slot < CAND_CAP) {
                    unsigned int idx = (unsigned int)(baseIdx + g * A);
                    g_cand[slot] = ((unsigned long long)__float_as_uint(iou) << 32)
                                 | (unsigned long long)(~idx);
                }
            }
        }
    }
    atomicMax(&g_posmax[pos], __float_as_uint(vmax));
}

#define PK_T 256
// Single block: radix-select exact top-100 keys, sort in LDS, threefry scores,
// top-10, gather positives.
__global__ void pos_kernel(const float* __restrict__ proposals,
                           const float* __restrict__ cls_prob,
                           const float* __restrict__ anchor_prob,
                           const float* __restrict__ gtp,
                           const int*   __restrict__ gtc,
                           float* __restrict__ out) {
    __shared__ unsigned int hist[4096];
    __shared__ int partial[PK_T];
    __shared__ unsigned long long cbuf[1024];
    __shared__ unsigned long long lst[100];
    __shared__ unsigned long long skeys[PK_T];
    __shared__ int selIdx[10];
    __shared__ int sh_d, sh_before, sh_cnt;

    int t = threadIdx.x;
    int C = g_candCount;
    if (C > CAND_CAP) C = CAND_CAP;
    int needTotal = C < 100 ? C : 100;

    int M = 0;
    if (C <= 1024) {
        for (int i = t; i < C; i += PK_T) cbuf[i] = g_cand[i];
        M = C;
        __syncthreads();
    } else {
        const int shifts[6] = {52, 40, 28, 16, 4, 0};
        const int nbits[6]  = {12, 12, 12, 12, 12, 4};
        unsigned long long lo = 0ull;
        int need = needTotal;
        int globalAbove = 0;
        for (int lvl = 0; lvl < 6; ++lvl) {
            int sh = shifts[lvl];
            int nb = 1 << nbits[lvl];
            unsigned long long hiMask = lvl ? ~((1ull << shifts[lvl - 1]) - 1ull) : 0ull;
            for (int i = t; i < nb; i += PK_T) hist[i] = 0u;
            __syncthreads();
            for (int i = t; i < C; i += PK_T) {
                unsigned long long key = g_cand[i];
                if ((key & hiMask) == lo)
                    atomicAdd(&hist[(unsigned)(key >> sh) & (unsigned)(nb - 1)], 1u);
            }
            __syncthreads();
            int chunk = (nb >= PK_T) ? (nb / PK_T) : 1;
            int nchunks = nb / chunk;
            int ps = 0;
            if (t < nchunks) for (int k2 = 0; k2 < chunk; ++k2) ps += (int)hist[t * chunk + k2];
            partial[t] = (t < nchunks) ? ps : 0;
            __syncthreads();
            if (t == 0) {
                int cum = 0, d = 0;
                for (int c = nchunks - 1; c >= 0; --c) {
                    if (cum + partial[c] >= need) {
                        for (int b2 = c * chunk + chunk - 1; b2 >= c * chunk; --b2) {
                            if (cum + (int)hist[b2] >= need) { d = b2; break; }
                            cum += (int)hist[b2];
                        }
                        break;
                    }
                    cum += partial[c];
                }
                sh_d = d; sh_before = cum;
            }
            __syncthreads();
            int d = sh_d, sBefore = sh_before;
            int tie = (int)hist[d];
            lo |= ((unsigned long long)(unsigned)d) << sh;
            int total = globalAbove + sBefore + tie;   // exact count of keys >= lo
            globalAbove += sBefore;
            need -= sBefore;
            if (total <= 1024) {                       // guaranteed by final level (keys unique)
                if (t == 0) sh_cnt = 0;
                __syncthreads();
                for (int i = t; i < C; i += PK_T) {
                    unsigned long long key = g_cand[i];
                    if (key >= lo) { int s2 = atomicAdd(&sh_cnt, 1); cbuf[s2] = key; }
                }
                __syncthreads();
                M = sh_cnt;
                break;
            }
            __syncthreads();
        }
    }

    // exact sorted top-needTotal via rank-count (keys unique -> ranks unique)
    for (int i = t; i < M; i += PK_T) {
        unsigned long long ki = cbuf[i];
        int r = 0;
        for (int j = 0; j < M; ++j) r += (cbuf[j] > ki) ? 1 : 0;
        if (r < needTotal) lst[r] = ki;
    }
    __syncthreads();

    // scores: rank i gets uniform(kp,100)[i]; top-10 (value desc, index asc)
    unsigned int kp0, kp1, kn0, kn1;
    derive_keys(kp0, kp1, kn0, kn1);
    unsigned long long sk = 0ull;
    if (t < needTotal) {
        float u = jax_uniform(kp0, kp1, (unsigned)t, 100u);
        sk = ((unsigned long long)__float_as_uint(u) << 32) | (unsigned long long)(~(unsigned)t);
    }
    skeys[t] = sk;
    __syncthreads();

    if (t == 0) {
        for (int j = 0; j < 10; ++j) {
            unsigned long long best = 0ull; int bi = 0;
            for (int i = 0; i < needTotal; ++i)
                if (skeys[i] > best) { best = skeys[i]; bi = i; }
            selIdx[j] = bi;
            skeys[bi] = 0ull;
        }
    }
    __syncthreads();

    if (t < 10) {
        unsigned long long key = lst[selIdx[t]];
        unsigned int fidx = ~(unsigned int)(key & 0xFFFFFFFFull);
        int a = fidx % A; unsigned int rest = fidx / A;
        int g = rest % G; rest /= G;
        int w = rest % W; rest /= W;
        int h = rest % H; int b = rest / H;
        int pos = (b * H + h) * W + w;

        out[t * 5 + 0] = (float)b;
        out[t * 5 + 1] = (float)h;
        out[t * 5 + 2] = (float)w;
        out[t * 5 + 3] = (float)g;
        out[t * 5 + 4] = (float)a;
        const float* pb = proposals + (size_t)(pos * A + a) * 4;
        for (int q = 0; q < 4; ++q) out[50 + t * 4 + q] = pb[q];
        const float* cp = cls_prob + (size_t)pos * K;
        for (int q = 0; q < K; ++q) out[90 + t * K + q] = cp[q];
        const float* gp = gtp + g * 4;
        for (int q = 0; q < 4; ++q) out[270 + t * 4 + q] = gp[q];
        out[310 + t] = (float)gtc[g];
        out[320 + t] = (float)a;
        const float* ap = anchor_prob + (size_t)pos * K;
        for (int q = 0; q < K; ++q) out[330 + t * K + q] = ap[q];
    }
}

// 32 blocks: per-block exact top-10 of uniforms among masked positions -> d_ws
__global__ void neg_part_kernel(unsigned long long* __restrict__ ws) {
    __shared__ unsigned long long red[NEG_T];
    int t = threadIdx.x;
    int bid = blockIdx.x;

    unsigned int kp0, kp1, kn0, kn1;
    derive_keys(kp0, kp1, kn0, kn1);

    unsigned long long top[10];
#pragma unroll
    for (int j = 0; j < 10; ++j) top[j] = 0ull;

    for (int pos = bid * NEG_T + t; pos < NPOS; pos += NEG_BLOCKS * NEG_T) {
        float m = __uint_as_float(g_posmax[pos]);
        if (m < THR) {
            float u = jax_uniform(kn0, kn1, (unsigned)pos, (unsigned)NPOS);
            unsigned long long key = ((unsigned long long)__float_as_uint(u) << 32)
                                   | (unsigned long long)(~(unsigned)pos);
#pragma unroll
            for (int j = 0; j < 10; ++j) {
                if (key > top[j]) { unsigned long long tmp = top[j]; top[j] = key; key = tmp; }
            }
        }
    }

    for (int r = 0; r < 10; ++r) {
        unsigned long long best = 0ull;
#pragma unroll
        for (int j = 0; j < 10; ++j) if (top[j] > best) best = top[j];
        red[t] = best;
        __syncthreads();
        for (int s = NEG_T / 2; s > 0; s >>= 1) {
            if (t < s && red[t + s] > red[t]) red[t] = red[t + s];
            __syncthreads();
        }
        unsigned long long win = red[0];
        if (t == 0) ws[bid * 10 + r] = win;
#pragma unroll
        for (int j = 0; j < 10; ++j) if (top[j] == win) top[j] = 0ull;
        __syncthreads();
    }
}

// 1 block: merge 320 keys -> global top-10, gather negatives
__global__ void neg_final_kernel(const unsigned long long* __restrict__ ws,
                                 const float* __restrict__ cls_prob,
                                 float* __restrict__ out) {
    __shared__ unsigned long long keys[NEG_BLOCKS * 10];
    __shared__ unsigned long long swin[10];
    int t = threadIdx.x;
    if (t < NEG_BLOCKS * 10) keys[t] = ws[t];
    __syncthreads();
    if (t < NEG_BLOCKS * 10) {
        unsigned long long k = keys[t];
        if (k != 0ull) {                       // zeros can't rank (>=100 real keys exist)
            int r = 0;
            for (int j = 0; j < NEG_BLOCKS * 10; ++j) r += (keys[j] > k) ? 1 : 0;
            if (r < 10) swin[r] = k;
        }
    }
    __syncthreads();

    if (t < 10) {
        unsigned long long win = swin[t];
        unsigned int pos_ = ~(unsigned int)(win & 0xFFFFFFFFull);
        int nb = pos_ / (H * W);
        int nh = (pos_ / W) % H;
        int nw = pos_ % W;
        out[510 + t * 3 + 0] = (float)nb;
        out[510 + t * 3 + 1] = (float)nh;
        out[510 + t * 3 + 2] = (float)nw;
        const float* cp = cls_prob + (size_t)pos_ * K;
        for (int q = 0; q < K; ++q) out[540 + t * K + q] = cp[q];
    }
}

// ---------------- launcher ----------------
extern "C" void kernel_launch(void* const* d_in, const int* in_sizes, int n_in,
                              void* d_out, int out_size, void* d_ws, size_t ws_size,
                              hipStream_t stream) {
    const float* proposals   = (const float*)d_in[0];
    const float* cls_prob    = (const float*)d_in[1];
    const float* anchor_prob = (const float*)d_in[2];
    const float* gtp         = (const float*)d_in[3];
    const int*   gtc         = (const int*)d_in[4];
    float* out = (float*)d_out;
    unsigned long long* ws = (unsigned long long*)d_ws;

    init_kernel<<<313, 256, 0, stream>>>();
    iou_kernel<<<(NPROP + 255) / 256, 256, 0, stream>>>(proposals, gtp);
    pos_kernel<<<1, PK_T, 0, stream>>>(proposals, cls_prob, anchor_prob, gtp, gtc, out);
    neg_part_kernel<<<NEG_BLOCKS, NEG_T, 0, stream>>>(ws);
    neg_final_kernel<<<1, 320, 0, stream>>>(ws, cls_prob, out);
}

// Round 3
// 73.715 us; speedup vs baseline: 8.0108x; 1.5161x over previous
//
#include <hip/hip_runtime.h>

// ---------------- problem constants ----------------
constexpr int B = 8, H = 100, W = 100, A = 9, G = 50, K = 18;
constexpr int NPROP = B * H * W * A;   // 720000
constexpr int NPOS  = B * H * W;       // 80000
constexpr int CAND_CAP = 65536;
constexpr float THR = 0.7f;

#define JAX_PARTITIONABLE 1

#define TPB 576                 // 9 waves; 576 = LCM-friendly: 64 positions * 9 anchors
#define NB_P 625                // producer blocks: 1152 proposals (128 positions) each
#define POS_BID NB_P            // 625
#define NEG_BID0 (NB_P + 1)     // 626
#define NB_NEG 32
#define GRID (NB_P + 1 + NB_NEG)  // 658 <= 768 resident capacity -> all co-resident

// ---------------- device state (zero at load; final block resets each launch) ----
__device__ int g_candCount;
__device__ int g_done;    // producers finished
__device__ int g_done2;   // neg blocks finished
__device__ unsigned long long g_cand[CAND_CAP];   // key = (delta23 << 32) | ~flat_idx
__device__ unsigned int g_negflag[NPOS];          // 1 = has iou >= 0.7 (plain stores, full overwrite)
__device__ unsigned long long g_negtop[NB_NEG * 10];

// ---------------- threefry2x32 (JAX-exact) ----------------
__device__ __forceinline__ unsigned int rotl32(unsigned int x, int r) {
    return (x << r) | (x >> (32 - r));
}
__device__ __forceinline__ void tfr(unsigned int& x0, unsigned int& x1, int r) {
    x0 += x1; x1 = rotl32(x1, r); x1 ^= x0;
}
__device__ void threefry2x32(unsigned int k0, unsigned int k1,
                             unsigned int c0, unsigned int c1,
                             unsigned int& o0, unsigned int& o1) {
    unsigned int ks2 = k0 ^ k1 ^ 0x1BD11BDAu;
    unsigned int x0 = c0 + k0, x1 = c1 + k1;
    tfr(x0,x1,13); tfr(x0,x1,15); tfr(x0,x1,26); tfr(x0,x1, 6);
    x0 += k1;  x1 += ks2 + 1u;
    tfr(x0,x1,17); tfr(x0,x1,29); tfr(x0,x1,16); tfr(x0,x1,24);
    x0 += ks2; x1 += k0 + 2u;
    tfr(x0,x1,13); tfr(x0,x1,15); tfr(x0,x1,26); tfr(x0,x1, 6);
    x0 += k0;  x1 += k1 + 3u;
    tfr(x0,x1,17); tfr(x0,x1,29); tfr(x0,x1,16); tfr(x0,x1,24);
    x0 += k1;  x1 += ks2 + 4u;
    tfr(x0,x1,13); tfr(x0,x1,15); tfr(x0,x1,26); tfr(x0,x1, 6);
    x0 += ks2; x1 += k0 + 5u;
    o0 = x0; o1 = x1;
}

__device__ void derive_keys(unsigned int& kp0, unsigned int& kp1,
                            unsigned int& kn0, unsigned int& kn1) {
#if JAX_PARTITIONABLE
    threefry2x32(0u, 42u, 0u, 0u, kp0, kp1);
    threefry2x32(0u, 42u, 0u, 1u, kn0, kn1);
#else
    unsigned int a0, b0, a1, b1;
    threefry2x32(0u, 42u, 0u, 2u, a0, b0);
    threefry2x32(0u, 42u, 1u, 3u, a1, b1);
    kp0 = a0; kp1 = a1; kn0 = b0; kn1 = b1;
#endif
}

__device__ float jax_uniform(unsigned int k0, unsigned int k1, unsigned int i, unsigned int n) {
    unsigned int bits;
#if JAX_PARTITIONABLE
    unsigned int o0, o1;
    threefry2x32(k0, k1, 0u, i, o0, o1);
    bits = o0 ^ o1;
#else
    unsigned int half = n >> 1;
    unsigned int o0, o1;
    if (i < half) { threefry2x32(k0, k1, i, i + half, o0, o1); bits = o0; }
    else          { threefry2x32(k0, k1, i - half, i, o0, o1); bits = o1; }
#endif
    unsigned int fb = (bits >> 9) | 0x3F800000u;
    return __uint_as_float(fb) - 1.0f;
}

// ---------------- the single fused kernel ----------------
__global__ __launch_bounds__(TPB) void fused_kernel(
        const float* __restrict__ proposals, const float* __restrict__ cls_prob,
        const float* __restrict__ anchor_prob, const float* __restrict__ gtp,
        const int* __restrict__ gtc, float* __restrict__ out) {
    __shared__ float4 sgt[G];
    __shared__ unsigned int sflag[128];
    __shared__ unsigned int hist[4096];
    __shared__ int sfx[256];
    __shared__ unsigned long long cbuf[256];
    __shared__ unsigned long long lst[100];
    __shared__ unsigned long long skeys[100];
    __shared__ unsigned long long mkeys[NB_NEG * 10];
    __shared__ unsigned long long swin[10];
    __shared__ unsigned long long wred[9];
    __shared__ unsigned long long sh_win;
    __shared__ int selIdx[10];
    __shared__ int sh_d, sh_before, sh_cnt;

    const int t = threadIdx.x;
    const int bid = blockIdx.x;

    if (bid < NB_P) {
        // ============ producer: IoU over 1152 proposals (128 positions) ============
        if (t < G) sgt[t] = reinterpret_cast<const float4*>(gtp)[t];
        if (t < 128) sflag[t] = 0u;
        __syncthreads();

        int p0 = bid * 1152 + t;
        float4 x0 = reinterpret_cast<const float4*>(proposals)[p0];
        float4 x1 = reinterpret_cast<const float4*>(proposals)[p0 + 576];
        float ap0 = __fmul_rn(__fsub_rn(x0.z, x0.x), __fsub_rn(x0.w, x0.y));
        float ap1 = __fmul_rn(__fsub_rn(x1.z, x1.x), __fsub_rn(x1.w, x1.y));
        int li = t / 9, a = t - li * 9;
        int pos0 = bid * 128 + li;
        int base0 = pos0 * (G * A) + a;
        int base1 = (pos0 + 64) * (G * A) + a;
        unsigned f0 = 0u, f1 = 0u;

        for (int g = 0; g < G; ++g) {
            float4 gb = sgt[g];
            float ag = __fmul_rn(__fsub_rn(gb.z, gb.x), __fsub_rn(gb.w, gb.y));
            // box 0
            {
                float dx = __fsub_rn(fminf(x0.z, gb.z), fmaxf(x0.x, gb.x));
                float dy = __fsub_rn(fminf(x0.w, gb.w), fmaxf(x0.y, gb.y));
                float inter = __fmul_rn(fmaxf(dx, 0.0f), fmaxf(dy, 0.0f));
                float den = __fadd_rn(__fsub_rn(__fadd_rn(ap0, ag), inter), 1e-8f);
                if (inter > __fmul_rn(0.699f, den)) {   // safe screen; exact only near/over thr
                    float iou = __fdiv_rn(inter, den);
                    if (iou >= THR) f0 = 1u;
                    if (iou > THR) {
                        int slot = atomicAdd(&g_candCount, 1);
                        if (slot < CAND_CAP) {
                            unsigned int delta = __float_as_uint(iou) - 0x3F333334u;
                            unsigned int idx = (unsigned int)(base0 + g * A);
                            g_cand[slot] = ((unsigned long long)delta << 32)
                                         | (unsigned long long)(~idx);
                        }
                    }
                }
            }
            // box 1
            {
                float dx = __fsub_rn(fminf(x1.z, gb.z), fmaxf(x1.x, gb.x));
                float dy = __fsub_rn(fminf(x1.w, gb.w), fmaxf(x1.y, gb.y));
                float inter = __fmul_rn(fmaxf(dx, 0.0f), fmaxf(dy, 0.0f));
                float den = __fadd_rn(__fsub_rn(__fadd_rn(ap1, ag), inter), 1e-8f);
                if (inter > __fmul_rn(0.699f, den)) {
                    float iou = __fdiv_rn(inter, den);
                    if (iou >= THR) f1 = 1u;
                    if (iou > THR) {
                        int slot = atomicAdd(&g_candCount, 1);
                        if (slot < CAND_CAP) {
                            unsigned int delta = __float_as_uint(iou) - 0x3F333334u;
                            unsigned int idx = (unsigned int)(base1 + g * A);
                            g_cand[slot] = ((unsigned long long)delta << 32)
                                         | (unsigned long long)(~idx);
                        }
                    }
                }
            }
        }
        if (f0) atomicOr(&sflag[li], 1u);
        if (f1) atomicOr(&sflag[li + 64], 1u);
        __syncthreads();
        if (t < 128) g_negflag[bid * 128 + t] = sflag[t];
        __syncthreads();
        if (t == 0)
            __hip_atomic_fetch_add(&g_done, 1, __ATOMIC_RELEASE, __HIP_MEMORY_SCOPE_AGENT);

    } else if (bid == POS_BID) {
        // ============ positive selection + final negative merge ============
        if (t == 0) {
            while (__hip_atomic_load(&g_done, __ATOMIC_ACQUIRE, __HIP_MEMORY_SCOPE_AGENT) < NB_P)
                __builtin_amdgcn_s_sleep(8);
        }
        __syncthreads();

        int C = __hip_atomic_load(&g_candCount, __ATOMIC_RELAXED, __HIP_MEMORY_SCOPE_AGENT);
        if (C > CAND_CAP) C = CAND_CAP;
        int needTotal = C < 100 ? C : 100;
        int M = 0;

        if (C <= 256) {
            for (int i = t; i < C; i += TPB) cbuf[i] = g_cand[i];
            __syncthreads();
            M = C;
        } else {
            // radix-select: find exact boundary so that #keys >= lo is in (need..256]
            unsigned long long lo = 0ull;
            int need = needTotal, globalAbove = 0;
            const int shf[5]  = {43, 31, 19, 7, 0};
            const int wd5[5]  = {12, 12, 12, 12, 7};
            for (int lvl = 0; lvl < 5; ++lvl) {
                int sh = shf[lvl], nb = 1 << wd5[lvl];
                unsigned long long hiMask = (~0ull) << (sh + wd5[lvl]);
                for (int i = t; i < nb; i += TPB) hist[i] = 0u;
                __syncthreads();
                for (int i = t; i < C; i += TPB) {
                    unsigned long long k2 = g_cand[i];
                    if ((k2 & hiMask) == lo)
                        atomicAdd(&hist[(unsigned)(k2 >> sh) & (unsigned)(nb - 1)], 1u);
                }
                __syncthreads();
                int chunk = nb / 256; if (!chunk) chunk = 1;
                int nch = nb / chunk;
                if (t < 256) {
                    int ps = 0;
                    if (t < nch) for (int q = 0; q < chunk; ++q) ps += (int)hist[t * chunk + q];
                    sfx[t] = ps;
                }
                __syncthreads();
                // parallel suffix-sum over 256 chunk-partials
                for (int s = 1; s < 256; s <<= 1) {
                    int v = 0;
                    if (t < 256) v = (t + s < 256) ? sfx[t + s] : 0;
                    __syncthreads();
                    if (t < 256) sfx[t] += v;
                    __syncthreads();
                }
                if (t < nch) {
                    int above = (t + 1 < 256) ? sfx[t + 1] : 0;
                    if (sfx[t] >= need && above < need) {   // unique boundary chunk
                        int cum = above;
                        for (int b2 = t * chunk + chunk - 1; b2 >= t * chunk; --b2) {
                            int hb = (int)hist[b2];
                            if (cum + hb >= need) { sh_d = b2; sh_before = cum; break; }
                            cum += hb;
                        }
                    }
                }
                __syncthreads();
                int d = sh_d, sb = sh_before;
                int tie = (int)hist[d];
                lo |= ((unsigned long long)(unsigned)d) << sh;
                int total = globalAbove + sb + tie;
                globalAbove += sb;
                need -= sb;
                __syncthreads();   // hist/sh_d reads done before next level or compaction
                if (total <= 256) {     // final level guarantees total <= ~228
                    if (t == 0) sh_cnt = 0;
                    __syncthreads();
                    for (int i = t; i < C; i += TPB) {
                        unsigned long long k2 = g_cand[i];
                        if (k2 >= lo) { int s2 = atomicAdd(&sh_cnt, 1); cbuf[s2] = k2; }
                    }
                    __syncthreads();
                    M = sh_cnt;
                    break;
                }
            }
        }

        // exact sorted top-needTotal via parallel rank-count (keys unique)
        for (int i = t; i < M; i += TPB) {
            unsigned long long ki = cbuf[i];
            int r = 0;
            for (int j = 0; j < M; ++j) r += (cbuf[j] > ki) ? 1 : 0;
            if (r < needTotal) lst[r] = ki;
        }
        __syncthreads();

        unsigned int kp0, kp1, kn0, kn1;
        derive_keys(kp0, kp1, kn0, kn1);
        if (t < needTotal) {
            float u = jax_uniform(kp0, kp1, (unsigned)t, 100u);
            skeys[t] = ((unsigned long long)__float_as_uint(u) << 32)
                     | (unsigned long long)(~(unsigned)t);
        }
        __syncthreads();
        if (t < needTotal) {
            unsigned long long s = skeys[t];
            int r = 0;
            for (int j = 0; j < needTotal; ++j) r += (skeys[j] > s) ? 1 : 0;
            if (r < 10) selIdx[r] = t;
        }
        __syncthreads();

        if (t < 10) {
            unsigned long long key = lst[selIdx[t]];
            unsigned int fidx = ~(unsigned int)(key & 0xFFFFFFFFull);
            int a = fidx % A; unsigned int rest = fidx / A;
            int g = rest % G; rest /= G;
            int w = rest % W; rest /= W;
            int h = rest % H; int b = rest / H;
            int pos = (b * H + h) * W + w;

            out[t * 5 + 0] = (float)b;
            out[t * 5 + 1] = (float)h;
            out[t * 5 + 2] = (float)w;
            out[t * 5 + 3] = (float)g;
            out[t * 5 + 4] = (float)a;
            const float* pb = proposals + (size_t)(pos * A + a) * 4;
            for (int q = 0; q < 4; ++q) out[50 + t * 4 + q] = pb[q];
            const float* cp = cls_prob + (size_t)pos * K;
            for (int q = 0; q < K; ++q) out[90 + t * K + q] = cp[q];
            const float* gp = gtp + g * 4;
            for (int q = 0; q < 4; ++q) out[270 + t * 4 + q] = gp[q];
            out[310 + t] = (float)gtc[g];
            out[320 + t] = (float)a;
            const float* ap = anchor_prob + (size_t)pos * K;
            for (int q = 0; q < K; ++q) out[330 + t * K + q] = ap[q];
        }

        // -------- final negative merge (after the 32 neg blocks) --------
        if (t == 0) {
            while (__hip_atomic_load(&g_done2, __ATOMIC_ACQUIRE, __HIP_MEMORY_SCOPE_AGENT) < NB_NEG)
                __builtin_amdgcn_s_sleep(8);
        }
        __syncthreads();
        if (t < NB_NEG * 10) mkeys[t] = g_negtop[t];
        __syncthreads();
        if (t < NB_NEG * 10) {
            unsigned long long k2 = mkeys[t];
            if (k2 != 0ull) {
                int r = 0;
                for (int j = 0; j < NB_NEG * 10; ++j) r += (mkeys[j] > k2) ? 1 : 0;
                if (r < 10) swin[r] = k2;
            }
        }
        __syncthreads();
        if (t < 10) {
            unsigned long long win = swin[t];
            unsigned int pos_ = ~(unsigned int)(win & 0xFFFFFFFFull);
            int nb2 = pos_ / (H * W);
            int nh = (pos_ / W) % H;
            int nw = pos_ % W;
            out[510 + t * 3 + 0] = (float)nb2;
            out[510 + t * 3 + 1] = (float)nh;
            out[510 + t * 3 + 2] = (float)nw;
            const float* cp = cls_prob + (size_t)pos_ * K;
            for (int q = 0; q < K; ++q) out[540 + t * K + q] = cp[q];
        }
        __syncthreads();
        if (t == 0) {    // reset launch state for next replay (everyone else is done)
            __hip_atomic_store(&g_candCount, 0, __ATOMIC_RELAXED, __HIP_MEMORY_SCOPE_AGENT);
            __hip_atomic_store(&g_done2, 0, __ATOMIC_RELAXED, __HIP_MEMORY_SCOPE_AGENT);
            __hip_atomic_store(&g_done, 0, __ATOMIC_RELEASE, __HIP_MEMORY_SCOPE_AGENT);
        }

    } else {
        // ============ negative sampling: 32 blocks, per-block top-10 ============
        int nbid = bid - NEG_BID0;
        if (t == 0) {
            while (__hip_atomic_load(&g_done, __ATOMIC_ACQUIRE, __HIP_MEMORY_SCOPE_AGENT) < NB_P)
                __builtin_amdgcn_s_sleep(8);
        }
        __syncthreads();

        unsigned int kp0, kp1, kn0, kn1;
        derive_keys(kp0, kp1, kn0, kn1);

        unsigned long long top[10];
#pragma unroll
        for (int j = 0; j < 10; ++j) top[j] = 0ull;

        for (int pos = nbid * TPB + t; pos < NPOS; pos += NB_NEG * TPB) {
            if (g_negflag[pos] == 0u) {
                float u = jax_uniform(kn0, kn1, (unsigned)pos, (unsigned)NPOS);
                unsigned long long key = ((unsigned long long)__float_as_uint(u) << 32)
                                       | (unsigned long long)(~(unsigned)pos);
#pragma unroll
                for (int j = 0; j < 10; ++j) {   // sorted-desc insert, static indices
                    if (key > top[j]) { unsigned long long tmp = top[j]; top[j] = key; key = tmp; }
                }
            }
        }

        int lane = t & 63, wid = t >> 6;
        for (int r = 0; r < 10; ++r) {
            unsigned long long w = top[0];     // top[] sorted desc
            for (int s = 1; s < 64; s <<= 1) {
                unsigned long long o = __shfl_xor(w, s);
                if (o > w) w = o;
            }
            if (lane == 0) wred[wid] = w;
            __syncthreads();
            if (t == 0) {
                unsigned long long m = wred[0];
                for (int i = 1; i < 9; ++i) if (wred[i] > m) m = wred[i];
                sh_win = m;
                g_negtop[nbid * 10 + r] = m;
            }
            __syncthreads();
            unsigned long long win = sh_win;
            if (top[0] == win) {
#pragma unroll
                for (int j = 0; j < 9; ++j) top[j] = top[j + 1];
                top[9] = 0ull;
            }
        }
        __syncthreads();
        if (t == 0)
            __hip_atomic_fetch_add(&g_done2, 1, __ATOMIC_RELEASE, __HIP_MEMORY_SCOPE_AGENT);
    }
}

// ---------------- launcher ----------------
extern "C" void kernel_launch(void* const* d_in, const int* in_sizes, int n_in,
                              void* d_out, int out_size, void* d_ws, size_t ws_size,
                              hipStream_t stream) {
    const float* proposals   = (const float*)d_in[0];
    const float* cls_prob    = (const float*)d_in[1];
    const float* anchor_prob = (const float*)d_in[2];
    const float* gtp         = (const float*)d_in[3];
    const int*   gtc         = (const int*)d_in[4];
    float* out = (float*)d_out;

    fused_kernel<<<GRID, TPB, 0, stream>>>(proposals, cls_prob, anchor_prob, gtp, gtc, out);
}

// Round 4
// 62.316 us; speedup vs baseline: 9.4762x; 1.1829x over previous
//
#include <hip/hip_runtime.h>

// ---------------- problem constants ----------------
constexpr int B = 8, H = 100, W = 100, A = 9, G = 50, K = 18;
constexpr int NPROP = B * H * W * A;   // 720000
constexpr int NPOS  = B * H * W;       // 80000
constexpr int CAND_CAP = 65536;
constexpr float THR = 0.7f;

#define JAX_PARTITIONABLE 1

#define TPB 576                  // 9 waves
#define NB_P 625                 // producers: 1152 proposals / 128 positions each
#define POS_BID NB_P             // consumer block id (last)
#define GRID (NB_P + 1)          // 626 blocks; <=768 co-resident at 3/CU
#define BLK_CAND 1024            // per-block LDS candidate cap (avg ~25 expected)

// ---------------- device state (zero at load; consumer resets each launch) ----
__device__ int g_candCount;
__device__ int g_done;
__device__ unsigned long long g_cand[CAND_CAP];      // key = (delta23<<32) | ~flat_idx
__device__ unsigned long long g_negtop[NB_P * 10];   // per-block neg top-10 (0-padded)

// ---------------- threefry2x32 (JAX-exact) ----------------
__device__ __forceinline__ unsigned int rotl32(unsigned int x, int r) {
    return (x << r) | (x >> (32 - r));
}
__device__ __forceinline__ void tfr(unsigned int& x0, unsigned int& x1, int r) {
    x0 += x1; x1 = rotl32(x1, r); x1 ^= x0;
}
__device__ void threefry2x32(unsigned int k0, unsigned int k1,
                             unsigned int c0, unsigned int c1,
                             unsigned int& o0, unsigned int& o1) {
    unsigned int ks2 = k0 ^ k1 ^ 0x1BD11BDAu;
    unsigned int x0 = c0 + k0, x1 = c1 + k1;
    tfr(x0,x1,13); tfr(x0,x1,15); tfr(x0,x1,26); tfr(x0,x1, 6);
    x0 += k1;  x1 += ks2 + 1u;
    tfr(x0,x1,17); tfr(x0,x1,29); tfr(x0,x1,16); tfr(x0,x1,24);
    x0 += ks2; x1 += k0 + 2u;
    tfr(x0,x1,13); tfr(x0,x1,15); tfr(x0,x1,26); tfr(x0,x1, 6);
    x0 += k0;  x1 += k1 + 3u;
    tfr(x0,x1,17); tfr(x0,x1,29); tfr(x0,x1,16); tfr(x0,x1,24);
    x0 += k1;  x1 += ks2 + 4u;
    tfr(x0,x1,13); tfr(x0,x1,15); tfr(x0,x1,26); tfr(x0,x1, 6);
    x0 += ks2; x1 += k0 + 5u;
    o0 = x0; o1 = x1;
}

__device__ void derive_keys(unsigned int& kp0, unsigned int& kp1,
                            unsigned int& kn0, unsigned int& kn1) {
#if JAX_PARTITIONABLE
    threefry2x32(0u, 42u, 0u, 0u, kp0, kp1);
    threefry2x32(0u, 42u, 0u, 1u, kn0, kn1);
#else
    unsigned int a0, b0, a1, b1;
    threefry2x32(0u, 42u, 0u, 2u, a0, b0);
    threefry2x32(0u, 42u, 1u, 3u, a1, b1);
    kp0 = a0; kp1 = a1; kn0 = b0; kn1 = b1;
#endif
}

__device__ float jax_uniform(unsigned int k0, unsigned int k1, unsigned int i, unsigned int n) {
    unsigned int bits;
#if JAX_PARTITIONABLE
    unsigned int o0, o1;
    threefry2x32(k0, k1, 0u, i, o0, o1);
    bits = o0 ^ o1;
#else
    unsigned int half = n >> 1;
    unsigned int o0, o1;
    if (i < half) { threefry2x32(k0, k1, i, i + half, o0, o1); bits = o0; }
    else          { threefry2x32(k0, k1, i - half, i, o0, o1); bits = o1; }
#endif
    unsigned int fb = (bits >> 9) | 0x3F800000u;
    return __uint_as_float(fb) - 1.0f;
}

// ---------------- the single fused kernel ----------------
__global__ __launch_bounds__(TPB) void fused_kernel(
        const float* __restrict__ proposals, const float* __restrict__ cls_prob,
        const float* __restrict__ anchor_prob, const float* __restrict__ gtp,
        const int* __restrict__ gtc, float* __restrict__ out) {
    // producer-path LDS
    __shared__ float4 sgt[G];
    __shared__ float  sga[G];
    __shared__ unsigned int sflag[128];
    __shared__ unsigned long long scand[BLK_CAND];
    __shared__ unsigned long long snk[128];
    __shared__ unsigned long long wk[10];
    __shared__ int sh_cnt, sh_base;
    // consumer-path LDS
    __shared__ unsigned int hist[4096];
    __shared__ int sfx[256];
    __shared__ unsigned long long cbuf[256];
    __shared__ unsigned long long lst[100];
    __shared__ unsigned long long skeys[100];
    __shared__ unsigned long long swin[10];
    __shared__ unsigned long long wred[9];
    __shared__ unsigned long long sh_win;
    __shared__ int selIdx[10];
    __shared__ int sh_d, sh_before;

    const int t = threadIdx.x;
    const int bid = blockIdx.x;

    if (bid < NB_P) {
        // ============ producer: IoU over 1152 proposals (128 positions) ============
        if (t < G) {
            float4 gb = reinterpret_cast<const float4*>(gtp)[t];
            sgt[t] = gb;
            sga[t] = __fmul_rn(__fsub_rn(gb.z, gb.x), __fsub_rn(gb.w, gb.y));
        }
        if (t < 128) sflag[t] = 0u;
        if (t == 0) sh_cnt = 0;
        __syncthreads();

        int p0 = bid * 1152 + t;
        float4 x0 = reinterpret_cast<const float4*>(proposals)[p0];
        float4 x1 = reinterpret_cast<const float4*>(proposals)[p0 + 576];
        float ap0 = __fmul_rn(__fsub_rn(x0.z, x0.x), __fsub_rn(x0.w, x0.y));
        float ap1 = __fmul_rn(__fsub_rn(x1.z, x1.x), __fsub_rn(x1.w, x1.y));
        int li = t / 9, a = t - li * 9;
        int base0 = (bid * 128 + li) * (G * A) + a;
        int base1 = (bid * 128 + 64 + li) * (G * A) + a;
        unsigned f0 = 0u, f1 = 0u;

        for (int g = 0; g < G; ++g) {
            float4 gb = sgt[g];
            float ag = sga[g];
            {
                float dx = __fsub_rn(fminf(x0.z, gb.z), fmaxf(x0.x, gb.x));
                float dy = __fsub_rn(fminf(x0.w, gb.w), fmaxf(x0.y, gb.y));
                float inter = __fmul_rn(fmaxf(dx, 0.0f), fmaxf(dy, 0.0f));
                float den = __fadd_rn(__fsub_rn(__fadd_rn(ap0, ag), inter), 1e-8f);
                if (inter > __fmul_rn(0.699f, den)) {   // safe screen (margin >> ulp)
                    float iou = __fdiv_rn(inter, den);
                    if (iou >= THR) f0 = 1u;
                    if (iou > THR) {
                        unsigned int delta = __float_as_uint(iou) - 0x3F333334u;
                        unsigned int idx = (unsigned int)(base0 + g * A);
                        unsigned long long key = ((unsigned long long)delta << 32)
                                               | (unsigned long long)(~idx);
                        int s = atomicAdd(&sh_cnt, 1);
                        if (s < BLK_CAND) scand[s] = key;
                        else { int gs = atomicAdd(&g_candCount, 1);
                               if (gs < CAND_CAP) g_cand[gs] = key; }
                    }
                }
            }
            {
                float dx = __fsub_rn(fminf(x1.z, gb.z), fmaxf(x1.x, gb.x));
                float dy = __fsub_rn(fminf(x1.w, gb.w), fmaxf(x1.y, gb.y));
                float inter = __fmul_rn(fmaxf(dx, 0.0f), fmaxf(dy, 0.0f));
                float den = __fadd_rn(__fsub_rn(__fadd_rn(ap1, ag), inter), 1e-8f);
                if (inter > __fmul_rn(0.699f, den)) {
                    float iou = __fdiv_rn(inter, den);
                    if (iou >= THR) f1 = 1u;
                    if (iou > THR) {
                        unsigned int delta = __float_as_uint(iou) - 0x3F333334u;
                        unsigned int idx = (unsigned int)(base1 + g * A);
                        unsigned long long key = ((unsigned long long)delta << 32)
                                               | (unsigned long long)(~idx);
                        int s = atomicAdd(&sh_cnt, 1);
                        if (s < BLK_CAND) scand[s] = key;
                        else { int gs = atomicAdd(&g_candCount, 1);
                               if (gs < CAND_CAP) g_cand[gs] = key; }
                    }
                }
            }
        }
        if (f0) atomicOr(&sflag[li], 1u);
        if (f1) atomicOr(&sflag[li + 64], 1u);
        if (t < 10) wk[t] = 0ull;
        __syncthreads();

        // bulk-append this block's candidates (one global atomic per block)
        int cnt = sh_cnt; if (cnt > BLK_CAND) cnt = BLK_CAND;
        if (t == 0) sh_base = atomicAdd(&g_candCount, cnt);
        // per-block negative keys for its 128 positions
        if (t < 128) {
            unsigned int kp0, kp1, kn0, kn1;
            derive_keys(kp0, kp1, kn0, kn1);
            unsigned long long key = 0ull;
            if (sflag[t] == 0u) {
                unsigned int pos = (unsigned)(bid * 128 + t);
                float u = jax_uniform(kn0, kn1, pos, (unsigned)NPOS);
                key = ((unsigned long long)__float_as_uint(u) << 32)
                    | (unsigned long long)(~pos);
            }
            snk[t] = key;
        }
        __syncthreads();
        int base = sh_base;
        for (int i = t; i < cnt; i += TPB)
            if (base + i < CAND_CAP) g_cand[base + i] = scand[i];
        if (t < 128) {
            unsigned long long k2 = snk[t];
            if (k2 != 0ull) {
                int r = 0;
                for (int j = 0; j < 128; ++j) r += (snk[j] > k2) ? 1 : 0;
                if (r < 10) wk[r] = k2;      // ranks unique (keys unique)
            }
        }
        __syncthreads();
        if (t < 10) g_negtop[bid * 10 + t] = wk[t];
        __syncthreads();
        if (t == 0)
            __hip_atomic_fetch_add(&g_done, 1, __ATOMIC_RELEASE, __HIP_MEMORY_SCOPE_AGENT);

    } else {
        // ============ consumer: positives select + negatives merge ============
        if (t == 0) {
            while (__hip_atomic_load(&g_done, __ATOMIC_ACQUIRE, __HIP_MEMORY_SCOPE_AGENT) < NB_P)
                __builtin_amdgcn_s_sleep(8);
        }
        __syncthreads();

        int C = __hip_atomic_load(&g_candCount, __ATOMIC_RELAXED, __HIP_MEMORY_SCOPE_AGENT);
        if (C > CAND_CAP) C = CAND_CAP;
        int needTotal = C < 100 ? C : 100;
        int M = 0;

        if (C <= 256) {
            for (int i = t; i < C; i += TPB) cbuf[i] = g_cand[i];
            __syncthreads();
            M = C;
        } else {
            // radix-select boundary lo s.t. #keys >= lo lands in (need..256]
            unsigned long long lo = 0ull;
            int need = needTotal, globalAbove = 0;
            const int shf[5] = {43, 31, 19, 7, 0};
            const int wd5[5] = {12, 12, 12, 12, 7};
            for (int lvl = 0; lvl < 5; ++lvl) {
                int sh = shf[lvl], nb = 1 << wd5[lvl];
                unsigned long long hiMask = (~0ull) << (sh + wd5[lvl]);
                for (int i = t; i < nb; i += TPB) hist[i] = 0u;
                __syncthreads();
                for (int i = t; i < C; i += TPB) {
                    unsigned long long k2 = g_cand[i];
                    if ((k2 & hiMask) == lo)
                        atomicAdd(&hist[(unsigned)(k2 >> sh) & (unsigned)(nb - 1)], 1u);
                }
                __syncthreads();
                int chunk = nb / 256; if (!chunk) chunk = 1;
                int nch = nb / chunk;
                if (t < 256) {
                    int ps = 0;
                    if (t < nch) for (int q = 0; q < chunk; ++q) ps += (int)hist[t * chunk + q];
                    sfx[t] = ps;
                }
                __syncthreads();
                for (int s = 1; s < 256; s <<= 1) {     // parallel suffix-sum
                    int v = 0;
                    if (t < 256) v = (t + s < 256) ? sfx[t + s] : 0;
                    __syncthreads();
                    if (t < 256) sfx[t] += v;
                    __syncthreads();
                }
                if (t < nch) {
                    int above = (t + 1 < 256) ? sfx[t + 1] : 0;
                    if (sfx[t] >= need && above < need) {
                        int cum = above;
                        for (int b2 = t * chunk + chunk - 1; b2 >= t * chunk; --b2) {
                            int hb = (int)hist[b2];
                            if (cum + hb >= need) { sh_d = b2; sh_before = cum; break; }
                            cum += hb;
                        }
                    }
                }
                __syncthreads();
                int d = sh_d, sb = sh_before;
                int tie = (int)hist[d];
                lo |= ((unsigned long long)(unsigned)d) << sh;
                int total = globalAbove + sb + tie;
                globalAbove += sb;
                need -= sb;
                __syncthreads();
                if (total <= 256) {
                    if (t == 0) sh_d = 0;   // reuse as compaction counter
                    __syncthreads();
                    for (int i = t; i < C; i += TPB) {
                        unsigned long long k2 = g_cand[i];
                        if (k2 >= lo) { int s2 = atomicAdd(&sh_d, 1); cbuf[s2] = k2; }
                    }
                    __syncthreads();
                    M = sh_d;
                    break;
                }
            }
        }

        // sorted top-needTotal via parallel rank-count (keys unique)
        for (int i = t; i < M; i += TPB) {
            unsigned long long ki = cbuf[i];
            int r = 0;
            for (int j = 0; j < M; ++j) r += (cbuf[j] > ki) ? 1 : 0;
            if (r < needTotal) lst[r] = ki;
        }
        __syncthreads();

        unsigned int kp0, kp1, kn0, kn1;
        derive_keys(kp0, kp1, kn0, kn1);
        if (t < needTotal) {
            float u = jax_uniform(kp0, kp1, (unsigned)t, 100u);
            skeys[t] = ((unsigned long long)__float_as_uint(u) << 32)
                     | (unsigned long long)(~(unsigned)t);
        }
        __syncthreads();
        if (t < needTotal) {
            unsigned long long s = skeys[t];
            int r = 0;
            for (int j = 0; j < needTotal; ++j) r += (skeys[j] > s) ? 1 : 0;
            if (r < 10) selIdx[r] = t;
        }
        __syncthreads();

        if (t < 10) {
            unsigned long long key = lst[selIdx[t]];
            unsigned int fidx = ~(unsigned int)(key & 0xFFFFFFFFull);
            int a = fidx % A; unsigned int rest = fidx / A;
            int g = rest % G; rest /= G;
            int w = rest % W; rest /= W;
            int h = rest % H; int b = rest / H;
            int pos = (b * H + h) * W + w;

            out[t * 5 + 0] = (float)b;
            out[t * 5 + 1] = (float)h;
            out[t * 5 + 2] = (float)w;
            out[t * 5 + 3] = (float)g;
            out[t * 5 + 4] = (float)a;
            const float* pb = proposals + (size_t)(pos * A + a) * 4;
            for (int q = 0; q < 4; ++q) out[50 + t * 4 + q] = pb[q];
            const float* cp = cls_prob + (size_t)pos * K;
            for (int q = 0; q < K; ++q) out[90 + t * K + q] = cp[q];
            const float* gp = gtp + g * 4;
            for (int q = 0; q < 4; ++q) out[270 + t * 4 + q] = gp[q];
            out[310 + t] = (float)gtc[g];
            out[320 + t] = (float)a;
            const float* ap = anchor_prob + (size_t)pos * K;
            for (int q = 0; q < K; ++q) out[330 + t * K + q] = ap[q];
        }

        // -------- negatives merge: 6250 keys -> global top-10 --------
        unsigned long long top[10];
#pragma unroll
        for (int j = 0; j < 10; ++j) top[j] = 0ull;
        for (int i = t; i < NB_P * 10; i += TPB) {
            unsigned long long key = g_negtop[i];
#pragma unroll
            for (int j = 0; j < 10; ++j) {   // sorted-desc insert, static indices
                if (key > top[j]) { unsigned long long tmp = top[j]; top[j] = key; key = tmp; }
            }
        }
        int lane = t & 63, wid = t >> 6;
        for (int r = 0; r < 10; ++r) {
            unsigned long long w = top[0];
            for (int s = 1; s < 64; s <<= 1) {
                unsigned long long o = __shfl_xor(w, s);
                if (o > w) w = o;
            }
            if (lane == 0) wred[wid] = w;
            __syncthreads();
            if (t == 0) {
                unsigned long long m = wred[0];
                for (int i = 1; i < 9; ++i) if (wred[i] > m) m = wred[i];
                sh_win = m;
                swin[r] = m;
            }
            __syncthreads();
            unsigned long long win = sh_win;
            if (top[0] == win) {
#pragma unroll
                for (int j = 0; j < 9; ++j) top[j] = top[j + 1];
                top[9] = 0ull;
            }
        }
        if (t < 10) {
            unsigned long long win = swin[t];
            unsigned int pos_ = ~(unsigned int)(win & 0xFFFFFFFFull);
            int nb2 = pos_ / (H * W);
            int nh = (pos_ / W) % H;
            int nw = pos_ % W;
            out[510 + t * 3 + 0] = (float)nb2;
            out[510 + t * 3 + 1] = (float)nh;
            out[510 + t * 3 + 2] = (float)nw;
            const float* cp = cls_prob + (size_t)pos_ * K;
            for (int q = 0; q < K; ++q) out[540 + t * K + q] = cp[q];
        }
        __syncthreads();
        if (t == 0) {   // reset for next replay (all other blocks already done)
            __hip_atomic_store(&g_candCount, 0, __ATOMIC_RELAXED, __HIP_MEMORY_SCOPE_AGENT);
            __hip_atomic_store(&g_done, 0, __ATOMIC_RELEASE, __HIP_MEMORY_SCOPE_AGENT);
        }
    }
}

// ---------------- launcher ----------------
extern "C" void kernel_launch(void* const* d_in, const int* in_sizes, int n_in,
                              void* d_out, int out_size, void* d_ws, size_t ws_size,
                              hipStream_t stream) {
    const float* proposals   = (const float*)d_in[0];
    const float* cls_prob    = (const float*)d_in[1];
    const float* anchor_prob = (const float*)d_in[2];
    const float* gtp         = (const float*)d_in[3];
    const int*   gtc         = (const int*)d_in[4];
    float* out = (float*)d_out;

    fused_kernel<<<GRID, TPB, 0, stream>>>(proposals, cls_prob, anchor_prob, gtp, gtc, out);
}

// Round 5
// 55.610 us; speedup vs baseline: 10.6188x; 1.1206x over previous
//
#include <hip/hip_runtime.h>

// ---------------- problem constants ----------------
constexpr int B = 8, H = 100, W = 100, A = 9, G = 50, K = 18;
constexpr int NPROP = B * H * W * A;   // 720000
constexpr int NPOS  = B * H * W;       // 80000
constexpr int CAND_CAP = 65536;
constexpr float THR = 0.7f;

#define JAX_PARTITIONABLE 1

#define TPB 576                  // 9 waves; 1152 proposals = 128 positions per block
#define NB_P 625                 // producer blocks
#define TPC 1024                 // consumer threads (16 waves)
#define BLK_CAND 1024            // per-block LDS candidate cap

// ---------------- device state (zero at load; consumer resets each launch) ----
__device__ int g_candCount;
__device__ unsigned long long g_cand[CAND_CAP];      // key = (delta23<<32) | ~flat_idx
__device__ unsigned long long g_negtop[NB_P * 10];   // per-block neg top-10 (0-padded)

// ---------------- threefry2x32 (JAX-exact) ----------------
__device__ __forceinline__ unsigned int rotl32(unsigned int x, int r) {
    return (x << r) | (x >> (32 - r));
}
__device__ __forceinline__ void tfr(unsigned int& x0, unsigned int& x1, int r) {
    x0 += x1; x1 = rotl32(x1, r); x1 ^= x0;
}
__device__ void threefry2x32(unsigned int k0, unsigned int k1,
                             unsigned int c0, unsigned int c1,
                             unsigned int& o0, unsigned int& o1) {
    unsigned int ks2 = k0 ^ k1 ^ 0x1BD11BDAu;
    unsigned int x0 = c0 + k0, x1 = c1 + k1;
    tfr(x0,x1,13); tfr(x0,x1,15); tfr(x0,x1,26); tfr(x0,x1, 6);
    x0 += k1;  x1 += ks2 + 1u;
    tfr(x0,x1,17); tfr(x0,x1,29); tfr(x0,x1,16); tfr(x0,x1,24);
    x0 += ks2; x1 += k0 + 2u;
    tfr(x0,x1,13); tfr(x0,x1,15); tfr(x0,x1,26); tfr(x0,x1, 6);
    x0 += k0;  x1 += k1 + 3u;
    tfr(x0,x1,17); tfr(x0,x1,29); tfr(x0,x1,16); tfr(x0,x1,24);
    x0 += k1;  x1 += ks2 + 4u;
    tfr(x0,x1,13); tfr(x0,x1,15); tfr(x0,x1,26); tfr(x0,x1, 6);
    x0 += ks2; x1 += k0 + 5u;
    o0 = x0; o1 = x1;
}

__device__ void derive_keys(unsigned int& kp0, unsigned int& kp1,
                            unsigned int& kn0, unsigned int& kn1) {
#if JAX_PARTITIONABLE
    threefry2x32(0u, 42u, 0u, 0u, kp0, kp1);
    threefry2x32(0u, 42u, 0u, 1u, kn0, kn1);
#else
    unsigned int a0, b0, a1, b1;
    threefry2x32(0u, 42u, 0u, 2u, a0, b0);
    threefry2x32(0u, 42u, 1u, 3u, a1, b1);
    kp0 = a0; kp1 = a1; kn0 = b0; kn1 = b1;
#endif
}

__device__ float jax_uniform(unsigned int k0, unsigned int k1, unsigned int i, unsigned int n) {
    unsigned int bits;
#if JAX_PARTITIONABLE
    unsigned int o0, o1;
    threefry2x32(k0, k1, 0u, i, o0, o1);
    bits = o0 ^ o1;
#else
    unsigned int half = n >> 1;
    unsigned int o0, o1;
    if (i < half) { threefry2x32(k0, k1, i, i + half, o0, o1); bits = o0; }
    else          { threefry2x32(k0, k1, i - half, i, o0, o1); bits = o1; }
#endif
    unsigned int fb = (bits >> 9) | 0x3F800000u;
    return __uint_as_float(fb) - 1.0f;
}

// ======================= kernel 1: producers =======================
__global__ __launch_bounds__(TPB) void prod_kernel(
        const float* __restrict__ proposals, const float* __restrict__ gtp) {
    __shared__ float4 sgt[G];
    __shared__ float  sga[G];
    __shared__ unsigned int sflag[128];
    __shared__ unsigned long long scand[BLK_CAND];
    __shared__ unsigned long long snk[128];
    __shared__ unsigned long long wk[10];
    __shared__ int sh_cnt, sh_base;

    const int t = threadIdx.x;
    const int bid = blockIdx.x;

    if (t < G) {
        float4 gb = reinterpret_cast<const float4*>(gtp)[t];
        sgt[t] = gb;
        sga[t] = __fmul_rn(__fsub_rn(gb.z, gb.x), __fsub_rn(gb.w, gb.y));
    }
    if (t < 128) sflag[t] = 0u;
    if (t == 0) sh_cnt = 0;
    __syncthreads();

    int p0 = bid * 1152 + t;
    float4 x0 = reinterpret_cast<const float4*>(proposals)[p0];
    float4 x1 = reinterpret_cast<const float4*>(proposals)[p0 + 576];
    float ap0 = __fmul_rn(__fsub_rn(x0.z, x0.x), __fsub_rn(x0.w, x0.y));
    float ap1 = __fmul_rn(__fsub_rn(x1.z, x1.x), __fsub_rn(x1.w, x1.y));
    int li = t / 9, a = t - li * 9;
    int base0 = (bid * 128 + li) * (G * A) + a;
    int base1 = (bid * 128 + 64 + li) * (G * A) + a;
    unsigned f0 = 0u, f1 = 0u;

    for (int g = 0; g < G; ++g) {
        float4 gb = sgt[g];
        float ag = sga[g];
        {
            float dx = __fsub_rn(fminf(x0.z, gb.z), fmaxf(x0.x, gb.x));
            float dy = __fsub_rn(fminf(x0.w, gb.w), fmaxf(x0.y, gb.y));
            float inter = __fmul_rn(fmaxf(dx, 0.0f), fmaxf(dy, 0.0f));
            float den = __fadd_rn(__fsub_rn(__fadd_rn(ap0, ag), inter), 1e-8f);
            if (inter > __fmul_rn(0.699f, den)) {   // safe screen (margin >> ulp)
                float iou = __fdiv_rn(inter, den);
                if (iou >= THR) f0 = 1u;
                if (iou > THR) {
                    unsigned int delta = __float_as_uint(iou) - 0x3F333334u;
                    unsigned int idx = (unsigned int)(base0 + g * A);
                    unsigned long long key = ((unsigned long long)delta << 32)
                                           | (unsigned long long)(~idx);
                    int s = atomicAdd(&sh_cnt, 1);
                    if (s < BLK_CAND) scand[s] = key;
                    else { int gs = atomicAdd(&g_candCount, 1);
                           if (gs < CAND_CAP) g_cand[gs] = key; }
                }
            }
        }
        {
            float dx = __fsub_rn(fminf(x1.z, gb.z), fmaxf(x1.x, gb.x));
            float dy = __fsub_rn(fminf(x1.w, gb.w), fmaxf(x1.y, gb.y));
            float inter = __fmul_rn(fmaxf(dx, 0.0f), fmaxf(dy, 0.0f));
            float den = __fadd_rn(__fsub_rn(__fadd_rn(ap1, ag), inter), 1e-8f);
            if (inter > __fmul_rn(0.699f, den)) {
                float iou = __fdiv_rn(inter, den);
                if (iou >= THR) f1 = 1u;
                if (iou > THR) {
                    unsigned int delta = __float_as_uint(iou) - 0x3F333334u;
                    unsigned int idx = (unsigned int)(base1 + g * A);
                    unsigned long long key = ((unsigned long long)delta << 32)
                                           | (unsigned long long)(~idx);
                    int s = atomicAdd(&sh_cnt, 1);
                    if (s < BLK_CAND) scand[s] = key;
                    else { int gs = atomicAdd(&g_candCount, 1);
                           if (gs < CAND_CAP) g_cand[gs] = key; }
                }
            }
        }
    }
    if (f0) atomicOr(&sflag[li], 1u);
    if (f1) atomicOr(&sflag[li + 64], 1u);
    if (t < 10) wk[t] = 0ull;
    __syncthreads();

    // bulk-append block candidates: one global atomic per block
    int cnt = sh_cnt; if (cnt > BLK_CAND) cnt = BLK_CAND;
    if (t == 0) sh_base = atomicAdd(&g_candCount, cnt);
    // negative keys for this block's 128 positions
    if (t < 128) {
        unsigned int kp0, kp1, kn0, kn1;
        derive_keys(kp0, kp1, kn0, kn1);
        unsigned long long key = 0ull;
        if (sflag[t] == 0u) {
            unsigned int pos = (unsigned)(bid * 128 + t);
            float u = jax_uniform(kn0, kn1, pos, (unsigned)NPOS);
            key = ((unsigned long long)__float_as_uint(u) << 32)
                | (unsigned long long)(~pos);
        }
        snk[t] = key;
    }
    __syncthreads();
    int base = sh_base;
    for (int i = t; i < cnt; i += TPB)
        if (base + i < CAND_CAP) g_cand[base + i] = scand[i];
    if (t < 128) {
        unsigned long long k2 = snk[t];
        if (k2 != 0ull) {
            int r = 0;
            for (int j = 0; j < 128; ++j) r += (snk[j] > k2) ? 1 : 0;
            if (r < 10) wk[r] = k2;       // ranks unique (keys unique)
        }
    }
    __syncthreads();
    if (t < 10) g_negtop[bid * 10 + t] = wk[t];
}

// ======================= kernel 2: consumer (1 block) =======================
__global__ __launch_bounds__(TPC) void cons_kernel(
        const float* __restrict__ proposals, const float* __restrict__ cls_prob,
        const float* __restrict__ anchor_prob, const float* __restrict__ gtp,
        const int* __restrict__ gtc, float* __restrict__ out) {
    __shared__ unsigned int hist[4096];
    __shared__ int sfx[256];
    __shared__ unsigned long long cbuf[256];
    __shared__ unsigned long long lst[100];
    __shared__ unsigned long long skeys[100];
    __shared__ unsigned long long swin[10];
    __shared__ unsigned long long wred[16];
    __shared__ unsigned long long sh_win;
    __shared__ int selIdx[10];
    __shared__ int sh_d, sh_before;

    const int t = threadIdx.x;

    int C = g_candCount;
    if (C > CAND_CAP) C = CAND_CAP;
    int needTotal = C < 100 ? C : 100;
    int M = 0;

    if (C <= 256) {
        for (int i = t; i < C; i += TPC) cbuf[i] = g_cand[i];
        __syncthreads();
        M = C;
    } else {
        // radix-select boundary lo s.t. #keys >= lo lands in (need..256]
        unsigned long long lo = 0ull;
        int need = needTotal, globalAbove = 0;
        const int shf[5] = {43, 31, 19, 7, 0};
        const int wd5[5] = {12, 12, 12, 12, 7};
        for (int lvl = 0; lvl < 5; ++lvl) {
            int sh = shf[lvl], nb = 1 << wd5[lvl];
            unsigned long long hiMask = (~0ull) << (sh + wd5[lvl]);
            for (int i = t; i < nb; i += TPC) hist[i] = 0u;
            __syncthreads();
            for (int i = t; i < C; i += TPC) {
                unsigned long long k2 = g_cand[i];
                if ((k2 & hiMask) == lo)
                    atomicAdd(&hist[(unsigned)(k2 >> sh) & (unsigned)(nb - 1)], 1u);
            }
            __syncthreads();
            int chunk = nb / 256; if (!chunk) chunk = 1;
            int nch = nb / chunk;
            if (t < 256) {
                int ps = 0;
                if (t < nch) for (int q = 0; q < chunk; ++q) ps += (int)hist[t * chunk + q];
                sfx[t] = ps;
            }
            __syncthreads();
            for (int s = 1; s < 256; s <<= 1) {     // parallel suffix-sum
                int v = 0;
                if (t < 256) v = (t + s < 256) ? sfx[t + s] : 0;
                __syncthreads();
                if (t < 256) sfx[t] += v;
                __syncthreads();
            }
            if (t < nch) {
                int above = (t + 1 < 256) ? sfx[t + 1] : 0;
                if (sfx[t] >= need && above < need) {
                    int cum = above;
                    for (int b2 = t * chunk + chunk - 1; b2 >= t * chunk; --b2) {
                        int hb = (int)hist[b2];
                        if (cum + hb >= need) { sh_d = b2; sh_before = cum; break; }
                        cum += hb;
                    }
                }
            }
            __syncthreads();
            int d = sh_d, sb = sh_before;
            int tie = (int)hist[d];
            lo |= ((unsigned long long)(unsigned)d) << sh;
            int total = globalAbove + sb + tie;
            globalAbove += sb;
            need -= sb;
            __syncthreads();
            if (total <= 256) {
                if (t == 0) sh_d = 0;   // reuse as compaction counter
                __syncthreads();
                for (int i = t; i < C; i += TPC) {
                    unsigned long long k2 = g_cand[i];
                    if (k2 >= lo) { int s2 = atomicAdd(&sh_d, 1); cbuf[s2] = k2; }
                }
                __syncthreads();
                M = sh_d;
                break;
            }
        }
    }

    // sorted top-needTotal via parallel rank-count (keys unique)
    for (int i = t; i < M; i += TPC) {
        unsigned long long ki = cbuf[i];
        int r = 0;
        for (int j = 0; j < M; ++j) r += (cbuf[j] > ki) ? 1 : 0;
        if (r < needTotal) lst[r] = ki;
    }
    __syncthreads();

    unsigned int kp0, kp1, kn0, kn1;
    derive_keys(kp0, kp1, kn0, kn1);
    if (t < needTotal) {
        float u = jax_uniform(kp0, kp1, (unsigned)t, 100u);
        skeys[t] = ((unsigned long long)__float_as_uint(u) << 32)
                 | (unsigned long long)(~(unsigned)t);
    }
    __syncthreads();
    if (t < needTotal) {
        unsigned long long s = skeys[t];
        int r = 0;
        for (int j = 0; j < needTotal; ++j) r += (skeys[j] > s) ? 1 : 0;
        if (r < 10) selIdx[r] = t;
    }
    __syncthreads();

    if (t < 10) {
        unsigned long long key = lst[selIdx[t]];
        unsigned int fidx = ~(unsigned int)(key & 0xFFFFFFFFull);
        int a = fidx % A; unsigned int rest = fidx / A;
        int g = rest % G; rest /= G;
        int w = rest % W; rest /= W;
        int h = rest % H; int b = rest / H;
        int pos = (b * H + h) * W + w;

        out[t * 5 + 0] = (float)b;
        out[t * 5 + 1] = (float)h;
        out[t * 5 + 2] = (float)w;
        out[t * 5 + 3] = (float)g;
        out[t * 5 + 4] = (float)a;
        const float* pb = proposals + (size_t)(pos * A + a) * 4;
        for (int q = 0; q < 4; ++q) out[50 + t * 4 + q] = pb[q];
        const float* cp = cls_prob + (size_t)pos * K;
        for (int q = 0; q < K; ++q) out[90 + t * K + q] = cp[q];
        const float* gp = gtp + g * 4;
        for (int q = 0; q < 4; ++q) out[270 + t * 4 + q] = gp[q];
        out[310 + t] = (float)gtc[g];
        out[320 + t] = (float)a;
        const float* ap = anchor_prob + (size_t)pos * K;
        for (int q = 0; q < K; ++q) out[330 + t * K + q] = ap[q];
    }

    // -------- negatives merge: 6250 keys -> global top-10 --------
    unsigned long long top[10];
#pragma unroll
    for (int j = 0; j < 10; ++j) top[j] = 0ull;
    for (int i = t; i < NB_P * 10; i += TPC) {
        unsigned long long key = g_negtop[i];
#pragma unroll
        for (int j = 0; j < 10; ++j) {   // sorted-desc insert, static indices
            if (key > top[j]) { unsigned long long tmp = top[j]; top[j] = key; key = tmp; }
        }
    }
    int lane = t & 63, wid = t >> 6;
    for (int r = 0; r < 10; ++r) {
        unsigned long long w = top[0];
        for (int s = 1; s < 64; s <<= 1) {
            unsigned long long o = __shfl_xor(w, s);
            if (o > w) w = o;
        }
        if (lane == 0) wred[wid] = w;
        __syncthreads();
        if (t == 0) {
            unsigned long long m = wred[0];
            for (int i = 1; i < 16; ++i) if (wred[i] > m) m = wred[i];
            sh_win = m;
            swin[r] = m;
        }
        __syncthreads();
        unsigned long long win = sh_win;
        if (top[0] == win) {
#pragma unroll
            for (int j = 0; j < 9; ++j) top[j] = top[j + 1];
            top[9] = 0ull;
        }
    }
    if (t < 10) {
        unsigned long long win = swin[t];
        unsigned int pos_ = ~(unsigned int)(win & 0xFFFFFFFFull);
        int nb2 = pos_ / (H * W);
        int nh = (pos_ / W) % H;
        int nw = pos_ % W;
        out[510 + t * 3 + 0] = (float)nb2;
        out[510 + t * 3 + 1] = (float)nh;
        out[510 + t * 3 + 2] = (float)nw;
        const float* cp = cls_prob + (size_t)pos_ * K;
        for (int q = 0; q < K; ++q) out[540 + t * K + q] = cp[q];
    }
    __syncthreads();
    if (t == 0) g_candCount = 0;    // reset for next replay
}

// ---------------- launcher ----------------
extern "C" void kernel_launch(void* const* d_in, const int* in_sizes, int n_in,
                              void* d_out, int out_size, void* d_ws, size_t ws_size,
                              hipStream_t stream) {
    const float* proposals   = (const float*)d_in[0];
    const float* cls_prob    = (const float*)d_in[1];
    const float* anchor_prob = (const float*)d_in[2];
    const float* gtp         = (const float*)d_in[3];
    const int*   gtc         = (const int*)d_in[4];
    float* out = (float*)d_out;

    prod_kernel<<<NB_P, TPB, 0, stream>>>(proposals, gtp);
    cons_kernel<<<1, TPC, 0, stream>>>(proposals, cls_prob, anchor_prob, gtp, gtc, out);
}

// Round 6
// 45.253 us; speedup vs baseline: 13.0492x; 1.2289x over previous
//
#include <hip/hip_runtime.h>

// ---------------- problem constants ----------------
constexpr int B = 8, H = 100, W = 100, A = 9, G = 50, K = 18;
constexpr int NPROP = B * H * W * A;   // 720000
constexpr int NPOS  = B * H * W;       // 80000
constexpr int CAND_CAP = 65536;
constexpr float THR = 0.7f;

#define JAX_PARTITIONABLE 1

#define TPB 576                  // 9 waves; 1152 proposals = 128 positions per block
#define NB_P 625                 // producer blocks
#define TPC 512                  // consumer threads (8 waves) x 2 blocks
#define BLK_CAND 1024            // per-block LDS candidate cap

// ---------------- device state (zero at load; consumer resets each launch) ----
__device__ int g_candCount;
__device__ unsigned int g_hist[4096];                // radix L0 hist (key>>43), built by producers
__device__ unsigned long long g_cand[CAND_CAP];      // key = (delta23<<32) | ~flat_idx
__device__ unsigned long long g_negtop[NB_P * 10];   // per-block neg top-10 (0-padded)

// ---------------- threefry2x32 (JAX-exact) ----------------
__device__ __forceinline__ unsigned int rotl32(unsigned int x, int r) {
    return (x << r) | (x >> (32 - r));
}
__device__ __forceinline__ void tfr(unsigned int& x0, unsigned int& x1, int r) {
    x0 += x1; x1 = rotl32(x1, r); x1 ^= x0;
}
__device__ void threefry2x32(unsigned int k0, unsigned int k1,
                             unsigned int c0, unsigned int c1,
                             unsigned int& o0, unsigned int& o1) {
    unsigned int ks2 = k0 ^ k1 ^ 0x1BD11BDAu;
    unsigned int x0 = c0 + k0, x1 = c1 + k1;
    tfr(x0,x1,13); tfr(x0,x1,15); tfr(x0,x1,26); tfr(x0,x1, 6);
    x0 += k1;  x1 += ks2 + 1u;
    tfr(x0,x1,17); tfr(x0,x1,29); tfr(x0,x1,16); tfr(x0,x1,24);
    x0 += ks2; x1 += k0 + 2u;
    tfr(x0,x1,13); tfr(x0,x1,15); tfr(x0,x1,26); tfr(x0,x1, 6);
    x0 += k0;  x1 += k1 + 3u;
    tfr(x0,x1,17); tfr(x0,x1,29); tfr(x0,x1,16); tfr(x0,x1,24);
    x0 += k1;  x1 += ks2 + 4u;
    tfr(x0,x1,13); tfr(x0,x1,15); tfr(x0,x1,26); tfr(x0,x1, 6);
    x0 += ks2; x1 += k0 + 5u;
    o0 = x0; o1 = x1;
}

__device__ void derive_keys(unsigned int& kp0, unsigned int& kp1,
                            unsigned int& kn0, unsigned int& kn1) {
#if JAX_PARTITIONABLE
    threefry2x32(0u, 42u, 0u, 0u, kp0, kp1);
    threefry2x32(0u, 42u, 0u, 1u, kn0, kn1);
#else
    unsigned int a0, b0, a1, b1;
    threefry2x32(0u, 42u, 0u, 2u, a0, b0);
    threefry2x32(0u, 42u, 1u, 3u, a1, b1);
    kp0 = a0; kp1 = a1; kn0 = b0; kn1 = b1;
#endif
}

__device__ float jax_uniform(unsigned int k0, unsigned int k1, unsigned int i, unsigned int n) {
    unsigned int bits;
#if JAX_PARTITIONABLE
    unsigned int o0, o1;
    threefry2x32(k0, k1, 0u, i, o0, o1);
    bits = o0 ^ o1;
#else
    unsigned int half = n >> 1;
    unsigned int o0, o1;
    if (i < half) { threefry2x32(k0, k1, i, i + half, o0, o1); bits = o0; }
    else          { threefry2x32(k0, k1, i - half, i, o0, o1); bits = o1; }
#endif
    unsigned int fb = (bits >> 9) | 0x3F800000u;
    return __uint_as_float(fb) - 1.0f;
}

// ======================= kernel 1: producers =======================
__global__ __launch_bounds__(TPB) void prod_kernel(
        const float* __restrict__ proposals, const float* __restrict__ gtp) {
    __shared__ float4 sgt[G];
    __shared__ float  sga[G];
    __shared__ unsigned int sflag[128];
    __shared__ unsigned long long scand[BLK_CAND];
    __shared__ unsigned long long snk[128];
    __shared__ unsigned long long wk[10];
    __shared__ int sh_cnt, sh_base;

    const int t = threadIdx.x;
    const int bid = blockIdx.x;

    if (t < G) {
        float4 gb = reinterpret_cast<const float4*>(gtp)[t];
        sgt[t] = gb;
        sga[t] = __fmul_rn(__fsub_rn(gb.z, gb.x), __fsub_rn(gb.w, gb.y));
    }
    if (t < 128) sflag[t] = 0u;
    if (t == 0) sh_cnt = 0;
    __syncthreads();

    int p0 = bid * 1152 + t;
    float4 x0 = reinterpret_cast<const float4*>(proposals)[p0];
    float4 x1 = reinterpret_cast<const float4*>(proposals)[p0 + 576];
    float ap0 = __fmul_rn(__fsub_rn(x0.z, x0.x), __fsub_rn(x0.w, x0.y));
    float ap1 = __fmul_rn(__fsub_rn(x1.z, x1.x), __fsub_rn(x1.w, x1.y));
    int li = t / 9, a = t - li * 9;
    int base0 = (bid * 128 + li) * (G * A) + a;
    int base1 = (bid * 128 + 64 + li) * (G * A) + a;
    unsigned f0 = 0u, f1 = 0u;

    for (int g = 0; g < G; ++g) {
        float4 gb = sgt[g];
        float ag = sga[g];
        {
            float dx = __fsub_rn(fminf(x0.z, gb.z), fmaxf(x0.x, gb.x));
            float dy = __fsub_rn(fminf(x0.w, gb.w), fmaxf(x0.y, gb.y));
            float inter = __fmul_rn(fmaxf(dx, 0.0f), fmaxf(dy, 0.0f));
            float s0 = __fadd_rn(ap0, ag);
            // screen: fail => iou <= 0.41/0.59 = 0.695 < 0.7 (margin >> ulp). exact path below.
            if (inter > __fmul_rn(0.41f, s0)) {
                float den = __fadd_rn(__fsub_rn(s0, inter), 1e-8f);
                float iou = __fdiv_rn(inter, den);
                if (iou >= THR) f0 = 1u;
                if (iou > THR) {
                    unsigned int delta = __float_as_uint(iou) - 0x3F333334u;
                    unsigned int idx = (unsigned int)(base0 + g * A);
                    unsigned long long key = ((unsigned long long)delta << 32)
                                           | (unsigned long long)(~idx);
                    int s = atomicAdd(&sh_cnt, 1);
                    if (s < BLK_CAND) scand[s] = key;
                    else { int gs = atomicAdd(&g_candCount, 1);
                           if (gs < CAND_CAP) { g_cand[gs] = key;
                               atomicAdd(&g_hist[(unsigned)(key >> 43)], 1u); } }
                }
            }
        }
        {
            float dx = __fsub_rn(fminf(x1.z, gb.z), fmaxf(x1.x, gb.x));
            float dy = __fsub_rn(fminf(x1.w, gb.w), fmaxf(x1.y, gb.y));
            float inter = __fmul_rn(fmaxf(dx, 0.0f), fmaxf(dy, 0.0f));
            float s1 = __fadd_rn(ap1, ag);
            if (inter > __fmul_rn(0.41f, s1)) {
                float den = __fadd_rn(__fsub_rn(s1, inter), 1e-8f);
                float iou = __fdiv_rn(inter, den);
                if (iou >= THR) f1 = 1u;
                if (iou > THR) {
                    unsigned int delta = __float_as_uint(iou) - 0x3F333334u;
                    unsigned int idx = (unsigned int)(base1 + g * A);
                    unsigned long long key = ((unsigned long long)delta << 32)
                                           | (unsigned long long)(~idx);
                    int s = atomicAdd(&sh_cnt, 1);
                    if (s < BLK_CAND) scand[s] = key;
                    else { int gs = atomicAdd(&g_candCount, 1);
                           if (gs < CAND_CAP) { g_cand[gs] = key;
                               atomicAdd(&g_hist[(unsigned)(key >> 43)], 1u); } }
                }
            }
        }
    }
    if (f0) atomicOr(&sflag[li], 1u);
    if (f1) atomicOr(&sflag[li + 64], 1u);
    if (t < 10) wk[t] = 0ull;
    __syncthreads();

    // bulk-append block candidates (one global atomic) + feed radix hist
    int cnt = sh_cnt; if (cnt > BLK_CAND) cnt = BLK_CAND;
    if (t == 0) sh_base = atomicAdd(&g_candCount, cnt);
    // negative keys for this block's 128 positions
    if (t < 128) {
        unsigned int kp0, kp1, kn0, kn1;
        derive_keys(kp0, kp1, kn0, kn1);
        unsigned long long key = 0ull;
        if (sflag[t] == 0u) {
            unsigned int pos = (unsigned)(bid * 128 + t);
            float u = jax_uniform(kn0, kn1, pos, (unsigned)NPOS);
            key = ((unsigned long long)__float_as_uint(u) << 32)
                | (unsigned long long)(~pos);
        }
        snk[t] = key;
    }
    __syncthreads();
    int base = sh_base;
    for (int i = t; i < cnt; i += TPB) {
        int gi = base + i;
        if (gi < CAND_CAP) {
            unsigned long long k2 = scand[i];
            g_cand[gi] = k2;
            atomicAdd(&g_hist[(unsigned)(k2 >> 43)], 1u);
        }
    }
    if (t < 128) {
        unsigned long long k2 = snk[t];
        if (k2 != 0ull) {
            int r = 0;
            for (int j = 0; j < 128; ++j) r += (snk[j] > k2) ? 1 : 0;
            if (r < 10) wk[r] = k2;       // ranks unique (keys unique)
        }
    }
    __syncthreads();
    if (t < 10) g_negtop[bid * 10 + t] = wk[t];
}

// ============ kernel 2: consumer — block 0 positives, block 1 negatives ============
__global__ __launch_bounds__(TPC) void cons_kernel(
        const float* __restrict__ proposals, const float* __restrict__ cls_prob,
        const float* __restrict__ anchor_prob, const float* __restrict__ gtp,
        const int* __restrict__ gtc, float* __restrict__ out) {
    __shared__ unsigned int hist[4096];
    __shared__ int sfx[256];
    __shared__ unsigned long long cbuf[BLK_CAND];
    __shared__ unsigned long long lst[100];
    __shared__ unsigned long long skeys[128];
    __shared__ unsigned long long swin[10];
    __shared__ unsigned long long wred[8];
    __shared__ int selIdx[10];
    __shared__ int sh_d, sh_before, sh_d2, sh_b2, sh_cnt;

    const int t = threadIdx.x;

    if (blockIdx.x == 0) {
        // ---------------- positives ----------------
        int C = g_candCount;
        if (C > CAND_CAP) C = CAND_CAP;
        int needTotal = C < 100 ? C : 100;
        int M = 0;

        if (C <= BLK_CAND) {
            for (int i = t; i < C; i += TPC) cbuf[i] = g_cand[i];
            __syncthreads();
            M = C;
        } else {
            int need = needTotal;
            // load producer-built hist
            for (int i = t; i < 4096; i += TPC) hist[i] = g_hist[i];
            __syncthreads();
            // 256 chunk totals (16 bins each)
            if (t < 256) {
                int ps = 0;
                for (int q = 0; q < 16; ++q) ps += (int)hist[t * 16 + q];
                sfx[t] = ps;
            }
            __syncthreads();
            // wave-0 suffix scan over 256 chunks; boundary bin search
            if (t < 64) {
                int lane = t;
                int c0 = sfx[4*lane+0], c1 = sfx[4*lane+1], c2 = sfx[4*lane+2], c3 = sfx[4*lane+3];
                int tot = c0 + c1 + c2 + c3;
                int acc = tot;
                for (int s = 1; s < 64; s <<= 1) {
                    int u = __shfl_down(acc, s);
                    if (lane + s < 64) acc += u;
                }
                int aboveG = acc - tot;           // count in chunks > 4*lane+3
                int CS3 = aboveG;
                int CS2 = CS3 + c3;
                int CS1 = CS2 + c2;
                int CS0 = CS1 + c1;
                int CSv[4] = {CS0, CS1, CS2, CS3};
                int cv[4]  = {c0, c1, c2, c3};
#pragma unroll
                for (int j = 0; j < 4; ++j) {
                    if (CSv[j] < need && CSv[j] + cv[j] >= need) {
                        int cum = CSv[j];
                        for (int b = (4*lane+j)*16 + 15; b >= (4*lane+j)*16; --b) {
                            int h = (int)hist[b];
                            if (cum + h >= need) { sh_d = b; sh_before = cum; break; }
                            cum += h;
                        }
                    }
                }
            }
            __syncthreads();
            int d = sh_d, sb = sh_before;
            int tie = (int)hist[d];
            unsigned long long lo = ((unsigned long long)(unsigned)d) << 43;
            int total = sb + tie;

            if (total > BLK_CAND) {
                // refine with 11 more bits (rare/never: needs >924 keys in one L0 bucket)
                __syncthreads();
                for (int i = t; i < 2048; i += TPC) hist[i] = 0u;
                __syncthreads();
                for (int i = t; i < C; i += TPC) {
                    unsigned long long k2 = g_cand[i];
                    if ((unsigned)(k2 >> 43) == (unsigned)d)
                        atomicAdd(&hist[(unsigned)(k2 >> 32) & 0x7FFu], 1u);
                }
                __syncthreads();
                if (t == 0) {
                    int cum = sb;
                    for (int b = 2047; b >= 0; --b) {
                        int h = (int)hist[b];
                        if (cum + h >= need) { sh_d2 = b; sh_b2 = cum; break; }
                        cum += h;
                    }
                }
                __syncthreads();
                lo |= ((unsigned long long)(unsigned)sh_d2) << 32;
            }

            if (t == 0) sh_cnt = 0;
            __syncthreads();
            for (int i = t; i < C; i += TPC) {
                unsigned long long k2 = g_cand[i];
                if (k2 >= lo) {
                    int s2 = atomicAdd(&sh_cnt, 1);
                    if (s2 < BLK_CAND) cbuf[s2] = k2;
                }
            }
            __syncthreads();
            M = sh_cnt < BLK_CAND ? sh_cnt : BLK_CAND;
        }

        // sorted top-needTotal via parallel rank-count (keys unique)
        for (int i = t; i < M; i += TPC) {
            unsigned long long ki = cbuf[i];
            int r = 0;
            for (int j = 0; j < M; ++j) r += (cbuf[j] > ki) ? 1 : 0;
            if (r < needTotal) lst[r] = ki;
        }
        __syncthreads();

        unsigned int kp0, kp1, kn0, kn1;
        derive_keys(kp0, kp1, kn0, kn1);
        if (t < needTotal) {
            float u = jax_uniform(kp0, kp1, (unsigned)t, 100u);
            skeys[t] = ((unsigned long long)__float_as_uint(u) << 32)
                     | (unsigned long long)(~(unsigned)t);
        }
        __syncthreads();
        if (t < needTotal) {
            unsigned long long s = skeys[t];
            int r = 0;
            for (int j = 0; j < needTotal; ++j) r += (skeys[j] > s) ? 1 : 0;
            if (r < 10) selIdx[r] = t;
        }
        __syncthreads();

        if (t < 10) {
            unsigned long long key = lst[selIdx[t]];
            unsigned int fidx = ~(unsigned int)(key & 0xFFFFFFFFull);
            int a = fidx % A; unsigned int rest = fidx / A;
            int g = rest % G; rest /= G;
            int w = rest % W; rest /= W;
            int h = rest % H; int b = rest / H;
            int pos = (b * H + h) * W + w;

            out[t * 5 + 0] = (float)b;
            out[t * 5 + 1] = (float)h;
            out[t * 5 + 2] = (float)w;
            out[t * 5 + 3] = (float)g;
            out[t * 5 + 4] = (float)a;
            const float* pb = proposals + (size_t)(pos * A + a) * 4;
            for (int q = 0; q < 4; ++q) out[50 + t * 4 + q] = pb[q];
            const float* cp = cls_prob + (size_t)pos * K;
            for (int q = 0; q < K; ++q) out[90 + t * K + q] = cp[q];
            const float* gp = gtp + g * 4;
            for (int q = 0; q < 4; ++q) out[270 + t * 4 + q] = gp[q];
            out[310 + t] = (float)gtc[g];
            out[320 + t] = (float)a;
            const float* ap = anchor_prob + (size_t)pos * K;
            for (int q = 0; q < K; ++q) out[330 + t * K + q] = ap[q];
        }

        // reset device state for next replay
        __syncthreads();
        for (int i = t; i < 4096; i += TPC) g_hist[i] = 0u;
        if (t == 0) g_candCount = 0;

    } else {
        // ---------------- negatives: merge 6250 per-block top-10s ----------------
        unsigned long long top[10];
#pragma unroll
        for (int j = 0; j < 10; ++j) top[j] = 0ull;
        for (int i = t; i < NB_P * 10; i += TPC) {
            unsigned long long key = g_negtop[i];
#pragma unroll
            for (int j = 0; j < 10; ++j) {   // sorted-desc insert, static indices
                if (key > top[j]) { unsigned long long tmp = top[j]; top[j] = key; key = tmp; }
            }
        }
        int lane = t & 63, wid = t >> 6;     // 8 waves
        for (int r = 0; r < 10; ++r) {
            unsigned long long w = top[0];
            for (int s = 1; s < 64; s <<= 1) {
                unsigned long long o = __shfl_xor(w, s);
                if (o > w) w = o;
            }
            if (lane == 0) wred[wid] = w;
            __syncthreads();
            unsigned long long m = wred[0];
#pragma unroll
            for (int i = 1; i < 8; ++i) { unsigned long long x = wred[i]; if (x > m) m = x; }
            if (t == 0) swin[r] = m;
            if (top[0] == m) {
#pragma unroll
                for (int j = 0; j < 9; ++j) top[j] = top[j + 1];
                top[9] = 0ull;
            }
            __syncthreads();
        }
        if (t < 10) {
            unsigned long long win = swin[t];
            unsigned int pos_ = ~(unsigned int)(win & 0xFFFFFFFFull);
            int nb2 = pos_ / (H * W);
            int nh = (pos_ / W) % H;
            int nw = pos_ % W;
            out[510 + t * 3 + 0] = (float)nb2;
            out[510 + t * 3 + 1] = (float)nh;
            out[510 + t * 3 + 2] = (float)nw;
            const float* cp = cls_prob + (size_t)pos_ * K;
            for (int q = 0; q < K; ++q) out[540 + t * K + q] = cp[q];
        }
    }
}

// ---------------- launcher ----------------
extern "C" void kernel_launch(void* const* d_in, const int* in_sizes, int n_in,
                              void* d_out, int out_size, void* d_ws, size_t ws_size,
                              hipStream_t stream) {
    const float* proposals   = (const float*)d_in[0];
    const float* cls_prob    = (const float*)d_in[1];
    const float* anchor_prob = (const float*)d_in[2];
    const float* gtp         = (const float*)d_in[3];
    const int*   gtc         = (const int*)d_in[4];
    float* out = (float*)d_out;

    prod_kernel<<<NB_P, TPB, 0, stream>>>(proposals, gtp);
    cons_kernel<<<2, TPC, 0, stream>>>(proposals, cls_prob, anchor_prob, gtp, gtc, out);
}

// Round 7
// 44.573 us; speedup vs baseline: 13.2484x; 1.0153x over previous
//
#include <hip/hip_runtime.h>

// ---------------- problem constants ----------------
constexpr int B = 8, H = 100, W = 100, A = 9, G = 50, K = 18;
constexpr int NPROP = B * H * W * A;   // 720000
constexpr int NPOS  = B * H * W;       // 80000
constexpr int CAND_CAP = 65536;
constexpr float THR = 0.7f;

#define JAX_PARTITIONABLE 1

#define TPB 576                  // 9 waves; 1152 proposals = 128 positions per block
#define NB_P 625                 // producer blocks
#define TPC 512                  // consumer threads (8 waves) x 2 blocks
#define BLK_CAND 1024            // per-block LDS candidate cap

// ---------------- device state (zero at load; consumer resets each launch) ----
__device__ int g_candCount;
__device__ unsigned int g_hist[4096];                // radix L0 hist (key>>43), built by producers
__device__ unsigned long long g_cand[CAND_CAP];      // key = (delta23<<32) | ~flat_idx
__device__ unsigned long long g_negtop[NB_P * 10];   // per-block neg top-10 (0-padded)

// ---------------- threefry2x32 (JAX-exact) ----------------
__device__ __forceinline__ unsigned int rotl32(unsigned int x, int r) {
    return (x << r) | (x >> (32 - r));
}
__device__ __forceinline__ void tfr(unsigned int& x0, unsigned int& x1, int r) {
    x0 += x1; x1 = rotl32(x1, r); x1 ^= x0;
}
__device__ void threefry2x32(unsigned int k0, unsigned int k1,
                             unsigned int c0, unsigned int c1,
                             unsigned int& o0, unsigned int& o1) {
    unsigned int ks2 = k0 ^ k1 ^ 0x1BD11BDAu;
    unsigned int x0 = c0 + k0, x1 = c1 + k1;
    tfr(x0,x1,13); tfr(x0,x1,15); tfr(x0,x1,26); tfr(x0,x1, 6);
    x0 += k1;  x1 += ks2 + 1u;
    tfr(x0,x1,17); tfr(x0,x1,29); tfr(x0,x1,16); tfr(x0,x1,24);
    x0 += ks2; x1 += k0 + 2u;
    tfr(x0,x1,13); tfr(x0,x1,15); tfr(x0,x1,26); tfr(x0,x1, 6);
    x0 += k0;  x1 += k1 + 3u;
    tfr(x0,x1,17); tfr(x0,x1,29); tfr(x0,x1,16); tfr(x0,x1,24);
    x0 += k1;  x1 += ks2 + 4u;
    tfr(x0,x1,13); tfr(x0,x1,15); tfr(x0,x1,26); tfr(x0,x1, 6);
    x0 += ks2; x1 += k0 + 5u;
    o0 = x0; o1 = x1;
}

__device__ void derive_keys(unsigned int& kp0, unsigned int& kp1,
                            unsigned int& kn0, unsigned int& kn1) {
#if JAX_PARTITIONABLE
    threefry2x32(0u, 42u, 0u, 0u, kp0, kp1);
    threefry2x32(0u, 42u, 0u, 1u, kn0, kn1);
#else
    unsigned int a0, b0, a1, b1;
    threefry2x32(0u, 42u, 0u, 2u, a0, b0);
    threefry2x32(0u, 42u, 1u, 3u, a1, b1);
    kp0 = a0; kp1 = a1; kn0 = b0; kn1 = b1;
#endif
}

__device__ float jax_uniform(unsigned int k0, unsigned int k1, unsigned int i, unsigned int n) {
    unsigned int bits;
#if JAX_PARTITIONABLE
    unsigned int o0, o1;
    threefry2x32(k0, k1, 0u, i, o0, o1);
    bits = o0 ^ o1;
#else
    unsigned int half = n >> 1;
    unsigned int o0, o1;
    if (i < half) { threefry2x32(k0, k1, i, i + half, o0, o1); bits = o0; }
    else          { threefry2x32(k0, k1, i - half, i, o0, o1); bits = o1; }
#endif
    unsigned int fb = (bits >> 9) | 0x3F800000u;
    return __uint_as_float(fb) - 1.0f;
}

// ======================= kernel 1: producers =======================
__global__ __launch_bounds__(TPB) void prod_kernel(
        const float* __restrict__ proposals, const float* __restrict__ gtp) {
    __shared__ float  s41[G];           // 0.41 * area_g  (only LDS read in hot loop, b32)
    __shared__ unsigned int sflag[128];
    __shared__ unsigned long long scand[BLK_CAND];
    __shared__ unsigned long long snk[128];
    __shared__ unsigned long long wk[10];
    __shared__ int sh_cnt, sh_base;

    const int t = threadIdx.x;
    const int bid = blockIdx.x;
    const float4* gtp4 = reinterpret_cast<const float4*>(gtp);   // uniform -> SMEM loads

    if (t < G) {
        float4 gb = gtp4[t];
        s41[t] = __fmul_rn(0.41f, __fmul_rn(__fsub_rn(gb.z, gb.x), __fsub_rn(gb.w, gb.y)));
    }
    if (t < 128) sflag[t] = 0u;
    if (t == 0) sh_cnt = 0;
    __syncthreads();

    int p0 = bid * 1152 + t;
    float4 x0 = reinterpret_cast<const float4*>(proposals)[p0];
    float4 x1 = reinterpret_cast<const float4*>(proposals)[p0 + 576];
    float ap0 = __fmul_rn(__fsub_rn(x0.z, x0.x), __fsub_rn(x0.w, x0.y));
    float ap1 = __fmul_rn(__fsub_rn(x1.z, x1.x), __fsub_rn(x1.w, x1.y));
    float a41_0 = __fmul_rn(0.41f, ap0);
    float a41_1 = __fmul_rn(0.41f, ap1);
    int li = t / 9, a = t - li * 9;
    int base0 = (bid * 128 + li) * (G * A) + a;
    int base1 = (bid * 128 + 64 + li) * (G * A) + a;
    unsigned f0 = 0u, f1 = 0u;

    for (int g = 0; g < G; ++g) {
        float4 gb = gtp4[g];            // wave-uniform -> scalar loads, no LDS/VMEM pressure
        float sg41 = s41[g];
        {
            float dx = __fsub_rn(fminf(x0.z, gb.z), fmaxf(x0.x, gb.x));
            float dy = __fsub_rn(fminf(x0.w, gb.w), fmaxf(x0.y, gb.y));
            float inter = __fmul_rn(fmaxf(dx, 0.0f), fmaxf(dy, 0.0f));
            // screen: fail => iou <= ~0.695 < 0.7 (margin >> ulp). exact path below.
            if (inter > __fadd_rn(a41_0, sg41)) {
                float ag = __fmul_rn(__fsub_rn(gb.z, gb.x), __fsub_rn(gb.w, gb.y));
                float den = __fadd_rn(__fsub_rn(__fadd_rn(ap0, ag), inter), 1e-8f);
                float iou = __fdiv_rn(inter, den);
                if (iou >= THR) f0 = 1u;
                if (iou > THR) {
                    unsigned int delta = __float_as_uint(iou) - 0x3F333334u;
                    unsigned int idx = (unsigned int)(base0 + g * A);
                    unsigned long long key = ((unsigned long long)delta << 32)
                                           | (unsigned long long)(~idx);
                    int s = atomicAdd(&sh_cnt, 1);
                    if (s < BLK_CAND) scand[s] = key;
                    else { int gs = atomicAdd(&g_candCount, 1);
                           if (gs < CAND_CAP) { g_cand[gs] = key;
                               atomicAdd(&g_hist[(unsigned)(key >> 43)], 1u); } }
                }
            }
        }
        {
            float dx = __fsub_rn(fminf(x1.z, gb.z), fmaxf(x1.x, gb.x));
            float dy = __fsub_rn(fminf(x1.w, gb.w), fmaxf(x1.y, gb.y));
            float inter = __fmul_rn(fmaxf(dx, 0.0f), fmaxf(dy, 0.0f));
            if (inter > __fadd_rn(a41_1, sg41)) {
                float ag = __fmul_rn(__fsub_rn(gb.z, gb.x), __fsub_rn(gb.w, gb.y));
                float den = __fadd_rn(__fsub_rn(__fadd_rn(ap1, ag), inter), 1e-8f);
                float iou = __fdiv_rn(inter, den);
                if (iou >= THR) f1 = 1u;
                if (iou > THR) {
                    unsigned int delta = __float_as_uint(iou) - 0x3F333334u;
                    unsigned int idx = (unsigned int)(base1 + g * A);
                    unsigned long long key = ((unsigned long long)delta << 32)
                                           | (unsigned long long)(~idx);
                    int s = atomicAdd(&sh_cnt, 1);
                    if (s < BLK_CAND) scand[s] = key;
                    else { int gs = atomicAdd(&g_candCount, 1);
                           if (gs < CAND_CAP) { g_cand[gs] = key;
                               atomicAdd(&g_hist[(unsigned)(key >> 43)], 1u); } }
                }
            }
        }
    }
    if (f0) atomicOr(&sflag[li], 1u);
    if (f1) atomicOr(&sflag[li + 64], 1u);
    if (t < 10) wk[t] = 0ull;
    __syncthreads();

    // bulk-append block candidates (one global atomic) + feed radix hist
    int cnt = sh_cnt; if (cnt > BLK_CAND) cnt = BLK_CAND;
    if (t == 0) sh_base = atomicAdd(&g_candCount, cnt);
    // negative keys for this block's 128 positions
    if (t < 128) {
        unsigned int kp0, kp1, kn0, kn1;
        derive_keys(kp0, kp1, kn0, kn1);
        unsigned long long key = 0ull;
        if (sflag[t] == 0u) {
            unsigned int pos = (unsigned)(bid * 128 + t);
            float u = jax_uniform(kn0, kn1, pos, (unsigned)NPOS);
            key = ((unsigned long long)__float_as_uint(u) << 32)
                | (unsigned long long)(~pos);
        }
        snk[t] = key;
    }
    __syncthreads();
    int base = sh_base;
    for (int i = t; i < cnt; i += TPB) {
        int gi = base + i;
        if (gi < CAND_CAP) {
            unsigned long long k2 = scand[i];
            g_cand[gi] = k2;
            atomicAdd(&g_hist[(unsigned)(k2 >> 43)], 1u);
        }
    }
    if (t < 128) {
        unsigned long long k2 = snk[t];
        if (k2 != 0ull) {
            int r = 0;
            for (int j = 0; j < 128; ++j) r += (snk[j] > k2) ? 1 : 0;
            if (r < 10) wk[r] = k2;       // ranks unique (keys unique)
        }
    }
    __syncthreads();
    if (t < 10) g_negtop[bid * 10 + t] = wk[t];
}

// ============ kernel 2: consumer — block 0 positives, block 1 negatives ============
__global__ __launch_bounds__(TPC) void cons_kernel(
        const float* __restrict__ proposals, const float* __restrict__ cls_prob,
        const float* __restrict__ anchor_prob, const float* __restrict__ gtp,
        const int* __restrict__ gtc, float* __restrict__ out) {
    __shared__ unsigned int hist[4096];
    __shared__ int sfx[256];
    __shared__ unsigned long long cbuf[BLK_CAND];
    __shared__ unsigned long long lst[100];
    __shared__ unsigned long long skeys[128];
    __shared__ unsigned long long swin[10];
    __shared__ unsigned long long wred[8];
    __shared__ int selIdx[10];
    __shared__ int sh_d, sh_before, sh_d2, sh_cnt;

    const int t = threadIdx.x;

    if (blockIdx.x == 0) {
        // ---------------- positives ----------------
        int C = g_candCount;
        if (C > CAND_CAP) C = CAND_CAP;
        int needTotal = C < 100 ? C : 100;
        int M = 0;

        if (C <= 256) {
            for (int i = t; i < C; i += TPC) cbuf[i] = g_cand[i];
            __syncthreads();
            M = C;
        } else {
            int need = needTotal;
            // load producer-built hist
            for (int i = t; i < 4096; i += TPC) hist[i] = g_hist[i];
            __syncthreads();
            // 256 chunk totals (16 bins each)
            if (t < 256) {
                int ps = 0;
                for (int q = 0; q < 16; ++q) ps += (int)hist[t * 16 + q];
                sfx[t] = ps;
            }
            __syncthreads();
            // wave-0 suffix scan over 256 chunks; boundary bin search
            if (t < 64) {
                int lane = t;
                int c0 = sfx[4*lane+0], c1 = sfx[4*lane+1], c2 = sfx[4*lane+2], c3 = sfx[4*lane+3];
                int tot = c0 + c1 + c2 + c3;
                int acc = tot;
                for (int s = 1; s < 64; s <<= 1) {
                    int u = __shfl_down(acc, s);
                    if (lane + s < 64) acc += u;
                }
                int aboveG = acc - tot;           // count in chunks > 4*lane+3
                int CS3 = aboveG;
                int CS2 = CS3 + c3;
                int CS1 = CS2 + c2;
                int CS0 = CS1 + c1;
                int CSv[4] = {CS0, CS1, CS2, CS3};
                int cv[4]  = {c0, c1, c2, c3};
#pragma unroll
                for (int j = 0; j < 4; ++j) {
                    if (CSv[j] < need && CSv[j] + cv[j] >= need) {
                        int cum = CSv[j];
                        for (int b = (4*lane+j)*16 + 15; b >= (4*lane+j)*16; --b) {
                            int h = (int)hist[b];
                            if (cum + h >= need) { sh_d = b; sh_before = cum; break; }
                            cum += h;
                        }
                    }
                }
            }
            __syncthreads();
            int d = sh_d, sb = sh_before;
            int tie = (int)hist[d];
            unsigned long long lo = ((unsigned long long)(unsigned)d) << 43;
            int total = sb + tie;

            if (total > BLK_CAND) {
                // refine with 11 more bits (needs >924 ties in one L0 bucket: ~never)
                __syncthreads();
                for (int i = t; i < 2048; i += TPC) hist[i] = 0u;
                __syncthreads();
                for (int i = t; i < C; i += TPC) {
                    unsigned long long k2 = g_cand[i];
                    if ((unsigned)(k2 >> 43) == (unsigned)d)
                        atomicAdd(&hist[(unsigned)(k2 >> 32) & 0x7FFu], 1u);
                }
                __syncthreads();
                if (t == 0) {
                    int cum = sb;
                    for (int b = 2047; b >= 0; --b) {
                        int h = (int)hist[b];
                        if (cum + h >= need) { sh_d2 = b; break; }
                        cum += h;
                    }
                }
                __syncthreads();
                lo |= ((unsigned long long)(unsigned)sh_d2) << 32;
            }

            if (t == 0) sh_cnt = 0;
            __syncthreads();
            for (int i = t; i < C; i += TPC) {
                unsigned long long k2 = g_cand[i];
                if (k2 >= lo) {
                    int s2 = atomicAdd(&sh_cnt, 1);
                    if (s2 < BLK_CAND) cbuf[s2] = k2;
                }
            }
            __syncthreads();
            M = sh_cnt < BLK_CAND ? sh_cnt : BLK_CAND;
        }

        // sorted top-needTotal via parallel rank-count (keys unique)
        for (int i = t; i < M; i += TPC) {
            unsigned long long ki = cbuf[i];
            int r = 0;
            for (int j = 0; j < M; ++j) r += (cbuf[j] > ki) ? 1 : 0;
            if (r < needTotal) lst[r] = ki;
        }
        __syncthreads();

        unsigned int kp0, kp1, kn0, kn1;
        derive_keys(kp0, kp1, kn0, kn1);
        if (t < needTotal) {
            float u = jax_uniform(kp0, kp1, (unsigned)t, 100u);
            skeys[t] = ((unsigned long long)__float_as_uint(u) << 32)
                     | (unsigned long long)(~(unsigned)t);
        }
        __syncthreads();
        if (t < needTotal) {
            unsigned long long s = skeys[t];
            int r = 0;
            for (int j = 0; j < needTotal; ++j) r += (skeys[j] > s) ? 1 : 0;
            if (r < 10) selIdx[r] = t;
        }
        __syncthreads();

        if (t < 10) {
            unsigned long long key = lst[selIdx[t]];
            unsigned int fidx = ~(unsigned int)(key & 0xFFFFFFFFull);
            int a = fidx % A; unsigned int rest = fidx / A;
            int g = rest % G; rest /= G;
            int w = rest % W; rest /= W;
            int h = rest % H; int b = rest / H;
            int pos = (b * H + h) * W + w;

            out[t * 5 + 0] = (float)b;
            out[t * 5 + 1] = (float)h;
            out[t * 5 + 2] = (float)w;
            out[t * 5 + 3] = (float)g;
            out[t * 5 + 4] = (float)a;
            const float* pb = proposals + (size_t)(pos * A + a) * 4;
            for (int q = 0; q < 4; ++q) out[50 + t * 4 + q] = pb[q];
            const float* cp = cls_prob + (size_t)pos * K;
            for (int q = 0; q < K; ++q) out[90 + t * K + q] = cp[q];
            const float* gp = gtp + g * 4;
            for (int q = 0; q < 4; ++q) out[270 + t * 4 + q] = gp[q];
            out[310 + t] = (float)gtc[g];
            out[320 + t] = (float)a;
            const float* ap = anchor_prob + (size_t)pos * K;
            for (int q = 0; q < K; ++q) out[330 + t * K + q] = ap[q];
        }

    } else {
        // ---------------- negatives: merge 6250 per-block top-10s ----------------
        unsigned long long top[10];
#pragma unroll
        for (int j = 0; j < 10; ++j) top[j] = 0ull;
        for (int i = t; i < NB_P * 10; i += TPC) {
            unsigned long long key = g_negtop[i];
#pragma unroll
            for (int j = 0; j < 10; ++j) {   // sorted-desc insert, static indices
                if (key > top[j]) { unsigned long long tmp = top[j]; top[j] = key; key = tmp; }
            }
        }
        int lane = t & 63, wid = t >> 6;     // 8 waves
        for (int r = 0; r < 10; ++r) {
            unsigned long long w = top[0];
            for (int s = 1; s < 64; s <<= 1) {
                unsigned long long o = __shfl_xor(w, s);
                if (o > w) w = o;
            }
            if (lane == 0) wred[wid] = w;
            __syncthreads();
            unsigned long long m = wred[0];
#pragma unroll
            for (int i = 1; i < 8; ++i) { unsigned long long x = wred[i]; if (x > m) m = x; }
            if (t == 0) swin[r] = m;
            if (top[0] == m) {
#pragma unroll
                for (int j = 0; j < 9; ++j) top[j] = top[j + 1];
                top[9] = 0ull;
            }
            __syncthreads();
        }
        if (t < 10) {
            unsigned long long win = swin[t];
            unsigned int pos_ = ~(unsigned int)(win & 0xFFFFFFFFull);
            int nb2 = pos_ / (H * W);
            int nh = (pos_ / W) % H;
            int nw = pos_ % W;
            out[510 + t * 3 + 0] = (float)nb2;
            out[510 + t * 3 + 1] = (float)nh;
            out[510 + t * 3 + 2] = (float)nw;
            const float* cp = cls_prob + (size_t)pos_ * K;
            for (int q = 0; q < K; ++q) out[540 + t * K + q] = cp[q];
        }
        // reset device state for next replay (parallel with block 0's tail)
        for (int i = t; i < 4096; i += TPC) g_hist[i] = 0u;
        if (t == 0) g_candCount = 0;
    }
}

// ---------------- launcher ----------------
extern "C" void kernel_launch(void* const* d_in, const int* in_sizes, int n_in,
                              void* d_out, int out_size, void* d_ws, size_t ws_size,
                              hipStream_t stream) {
    const float* proposals   = (const float*)d_in[0];
    const float* cls_prob    = (const float*)d_in[1];
    const float* anchor_prob = (const float*)d_in[2];
    const float* gtp         = (const float*)d_in[3];
    const int*   gtc         = (const int*)d_in[4];
    float* out = (float*)d_out;

    prod_kernel<<<NB_P, TPB, 0, stream>>>(proposals, gtp);
    cons_kernel<<<2, TPC, 0, stream>>>(proposals, cls_prob, anchor_prob, gtp, gtc, out);
}

// Round 12
// 44.085 us; speedup vs baseline: 13.3948x; 1.0111x over previous
//
#include <hip/hip_runtime.h>

// ---------------- problem constants ----------------
constexpr int B = 8, H = 100, W = 100, A = 9, G = 50, K = 18;
constexpr int NPROP = B * H * W * A;   // 720000
constexpr int NPOS  = B * H * W;       // 80000
constexpr int CAND_CAP = 65536;
constexpr float THR = 0.7f;

#define JAX_PARTITIONABLE 1

#define TPB 576                  // 9 waves; 1152 proposals = 128 positions per block
#define NB_P 625                 // producer blocks
#define TPC 512                  // consumer threads (8 waves) x 2 blocks
#define BLK_CAND 1024            // per-block LDS candidate cap
#define REFINE_THR 384           // cap rank-count M (refine fixes all delta bits)

// ---------------- device state (zero at load; consumer resets each launch) ----
__device__ int g_candCount;
__device__ unsigned int g_hist[4096];                // bins 0..153 used (key>>43)
__device__ unsigned long long g_cand[CAND_CAP];      // key = (delta23<<32) | ~flat_idx
__device__ unsigned long long g_negtop[NB_P * 10];   // per-block neg top-10 (0-padded)

// ---------------- threefry2x32 (JAX-exact) ----------------
__device__ __forceinline__ unsigned int rotl32(unsigned int x, int r) {
    return (x << r) | (x >> (32 - r));
}
__device__ __forceinline__ void tfr(unsigned int& x0, unsigned int& x1, int r) {
    x0 += x1; x1 = rotl32(x1, r); x1 ^= x0;
}
__device__ void threefry2x32(unsigned int k0, unsigned int k1,
                             unsigned int c0, unsigned int c1,
                             unsigned int& o0, unsigned int& o1) {
    unsigned int ks2 = k0 ^ k1 ^ 0x1BD11BDAu;
    unsigned int x0 = c0 + k0, x1 = c1 + k1;
    tfr(x0,x1,13); tfr(x0,x1,15); tfr(x0,x1,26); tfr(x0,x1, 6);
    x0 += k1;  x1 += ks2 + 1u;
    tfr(x0,x1,17); tfr(x0,x1,29); tfr(x0,x1,16); tfr(x0,x1,24);
    x0 += ks2; x1 += k0 + 2u;
    tfr(x0,x1,13); tfr(x0,x1,15); tfr(x0,x1,26); tfr(x0,x1, 6);
    x0 += k0;  x1 += k1 + 3u;
    tfr(x0,x1,17); tfr(x0,x1,29); tfr(x0,x1,16); tfr(x0,x1,24);
    x0 += k1;  x1 += ks2 + 4u;
    tfr(x0,x1,13); tfr(x0,x1,15); tfr(x0,x1,26); tfr(x0,x1, 6);
    x0 += ks2; x1 += k0 + 5u;
    o0 = x0; o1 = x1;
}

__device__ void derive_keys(unsigned int& kp0, unsigned int& kp1,
                            unsigned int& kn0, unsigned int& kn1) {
#if JAX_PARTITIONABLE
    threefry2x32(0u, 42u, 0u, 0u, kp0, kp1);
    threefry2x32(0u, 42u, 0u, 1u, kn0, kn1);
#else
    unsigned int a0, b0, a1, b1;
    threefry2x32(0u, 42u, 0u, 2u, a0, b0);
    threefry2x32(0u, 42u, 1u, 3u, a1, b1);
    kp0 = a0; kp1 = a1; kn0 = b0; kn1 = b1;
#endif
}

__device__ float jax_uniform(unsigned int k0, unsigned int k1, unsigned int i, unsigned int n) {
    unsigned int bits;
#if JAX_PARTITIONABLE
    unsigned int o0, o1;
    threefry2x32(k0, k1, 0u, i, o0, o1);
    bits = o0 ^ o1;
#else
    unsigned int half = n >> 1;
    unsigned int o0, o1;
    if (i < half) { threefry2x32(k0, k1, i, i + half, o0, o1); bits = o0; }
    else          { threefry2x32(k0, k1, i - half, i, o0, o1); bits = o1; }
#endif
    unsigned int fb = (bits >> 9) | 0x3F800000u;
    return __uint_as_float(fb) - 1.0f;
}

// ======================= kernel 1: producers (R7 verbatim) =======================
__global__ __launch_bounds__(TPB) void prod_kernel(
        const float* __restrict__ proposals, const float* __restrict__ gtp) {
    __shared__ float  s41[G];           // 0.41 * area_g  (only LDS read in hot loop)
    __shared__ unsigned int sflag[128];
    __shared__ unsigned long long scand[BLK_CAND];
    __shared__ unsigned long long snk[128];
    __shared__ unsigned long long wk[10];
    __shared__ int sh_cnt, sh_base;

    const int t = threadIdx.x;
    const int bid = blockIdx.x;
    const float4* gtp4 = reinterpret_cast<const float4*>(gtp);   // uniform -> scalar loads

    if (t < G) {
        float4 gb = gtp4[t];
        s41[t] = __fmul_rn(0.41f, __fmul_rn(__fsub_rn(gb.z, gb.x), __fsub_rn(gb.w, gb.y)));
    }
    if (t < 128) sflag[t] = 0u;
    if (t == 0) sh_cnt = 0;
    __syncthreads();

    int p0 = bid * 1152 + t;
    float4 x0 = reinterpret_cast<const float4*>(proposals)[p0];
    float4 x1 = reinterpret_cast<const float4*>(proposals)[p0 + 576];
    float ap0 = __fmul_rn(__fsub_rn(x0.z, x0.x), __fsub_rn(x0.w, x0.y));
    float ap1 = __fmul_rn(__fsub_rn(x1.z, x1.x), __fsub_rn(x1.w, x1.y));
    float a41_0 = __fmul_rn(0.41f, ap0);
    float a41_1 = __fmul_rn(0.41f, ap1);
    int li = t / 9, a = t - li * 9;
    int base0 = (bid * 128 + li) * (G * A) + a;
    int base1 = (bid * 128 + 64 + li) * (G * A) + a;
    unsigned f0 = 0u, f1 = 0u;

    for (int g = 0; g < G; ++g) {
        float4 gb = gtp4[g];            // wave-uniform -> scalar loads
        float sg41 = s41[g];
        {
            float dx = __fsub_rn(fminf(x0.z, gb.z), fmaxf(x0.x, gb.x));
            float dy = __fsub_rn(fminf(x0.w, gb.w), fmaxf(x0.y, gb.y));
            float inter = __fmul_rn(fmaxf(dx, 0.0f), fmaxf(dy, 0.0f));
            // screen: fail => iou <= ~0.695 < 0.7 (margin >> ulp). exact path below.
            if (inter > __fadd_rn(a41_0, sg41)) {
                float ag = __fmul_rn(__fsub_rn(gb.z, gb.x), __fsub_rn(gb.w, gb.y));
                float den = __fadd_rn(__fsub_rn(__fadd_rn(ap0, ag), inter), 1e-8f);
                float iou = __fdiv_rn(inter, den);
                if (iou >= THR) f0 = 1u;
                if (iou > THR) {
                    unsigned int delta = __float_as_uint(iou) - 0x3F333334u;
                    unsigned int idx = (unsigned int)(base0 + g * A);
                    unsigned long long key = ((unsigned long long)delta << 32)
                                           | (unsigned long long)(~idx);
                    int s = atomicAdd(&sh_cnt, 1);
                    if (s < BLK_CAND) scand[s] = key;
                    else { int gs = atomicAdd(&g_candCount, 1);
                           if (gs < CAND_CAP) { g_cand[gs] = key;
                               atomicAdd(&g_hist[(unsigned)(key >> 43)], 1u); } }
                }
            }
        }
        {
            float dx = __fsub_rn(fminf(x1.z, gb.z), fmaxf(x1.x, gb.x));
            float dy = __fsub_rn(fminf(x1.w, gb.w), fmaxf(x1.y, gb.y));
            float inter = __fmul_rn(fmaxf(dx, 0.0f), fmaxf(dy, 0.0f));
            if (inter > __fadd_rn(a41_1, sg41)) {
                float ag = __fmul_rn(__fsub_rn(gb.z, gb.x), __fsub_rn(gb.w, gb.y));
                float den = __fadd_rn(__fsub_rn(__fadd_rn(ap1, ag), inter), 1e-8f);
                float iou = __fdiv_rn(inter, den);
                if (iou >= THR) f1 = 1u;
                if (iou > THR) {
                    unsigned int delta = __float_as_uint(iou) - 0x3F333334u;
                    unsigned int idx = (unsigned int)(base1 + g * A);
                    unsigned long long key = ((unsigned long long)delta << 32)
                                           | (unsigned long long)(~idx);
                    int s = atomicAdd(&sh_cnt, 1);
                    if (s < BLK_CAND) scand[s] = key;
                    else { int gs = atomicAdd(&g_candCount, 1);
                           if (gs < CAND_CAP) { g_cand[gs] = key;
                               atomicAdd(&g_hist[(unsigned)(key >> 43)], 1u); } }
                }
            }
        }
    }
    if (f0) atomicOr(&sflag[li], 1u);
    if (f1) atomicOr(&sflag[li + 64], 1u);
    if (t < 10) wk[t] = 0ull;
    __syncthreads();

    // bulk-append block candidates (one global atomic) + feed radix hist
    int cnt = sh_cnt; if (cnt > BLK_CAND) cnt = BLK_CAND;
    if (t == 0) sh_base = atomicAdd(&g_candCount, cnt);
    if (t < 128) {
        unsigned int kp0, kp1, kn0, kn1;
        derive_keys(kp0, kp1, kn0, kn1);
        unsigned long long key = 0ull;
        if (sflag[t] == 0u) {
            unsigned int pos = (unsigned)(bid * 128 + t);
            float u = jax_uniform(kn0, kn1, pos, (unsigned)NPOS);
            key = ((unsigned long long)__float_as_uint(u) << 32)
                | (unsigned long long)(~pos);
        }
        snk[t] = key;
    }
    __syncthreads();
    int base = sh_base;
    for (int i = t; i < cnt; i += TPB) {
        int gi = base + i;
        if (gi < CAND_CAP) {
            unsigned long long k2 = scand[i];
            g_cand[gi] = k2;
            atomicAdd(&g_hist[(unsigned)(k2 >> 43)], 1u);
        }
    }
    if (t < 128) {
        unsigned long long k2 = snk[t];
        if (k2 != 0ull) {
            int r = 0;
            for (int j = 0; j < 128; ++j) r += (snk[j] > k2) ? 1 : 0;
            if (r < 10) wk[r] = k2;       // ranks unique (keys unique)
        }
    }
    __syncthreads();
    if (t < 10) g_negtop[bid * 10 + t] = wk[t];
}

// ============ kernel 2: consumer — block 0 positives, block 1 negatives ============
__global__ __launch_bounds__(TPC) void cons_kernel(
        const float* __restrict__ proposals, const float* __restrict__ cls_prob,
        const float* __restrict__ anchor_prob, const float* __restrict__ gtp,
        const int* __restrict__ gtc, float* __restrict__ out) {
    __shared__ unsigned int hist[4096];
    __shared__ int sfx[256];
    __shared__ unsigned long long cbuf[BLK_CAND];
    __shared__ unsigned long long lst[100];
    __shared__ unsigned long long skeys[128];
    __shared__ unsigned long long swin[10];
    __shared__ unsigned long long wred[8];
    __shared__ int selIdx[10];
    __shared__ int s_g[10], s_a[10], s_pos[10], s_bb[10], s_hh[10], s_ww[10], s_npos[10];
    __shared__ int sh_d, sh_before, sh_d2, sh_cnt;

    const int t = threadIdx.x;

    if (blockIdx.x == 0) {
        // ---------------- positives ----------------
        int C = g_candCount;
        if (C > CAND_CAP) C = CAND_CAP;
        int needTotal = C < 100 ? C : 100;
        int M = 0;

        if (C <= 256) {
            for (int i = t; i < C; i += TPC) cbuf[i] = g_cand[i];
            __syncthreads();
            M = C;
        } else {
            int need = needTotal;
            for (int i = t; i < 4096; i += TPC) hist[i] = g_hist[i];
            __syncthreads();
            if (t < 256) {
                int ps = 0;
                for (int q = 0; q < 16; ++q) ps += (int)hist[t * 16 + q];
                sfx[t] = ps;
            }
            __syncthreads();
            // wave-0 suffix scan over 256 chunks; boundary bin search (R7 verbatim)
            if (t < 64) {
                int lane = t;
                int c0 = sfx[4*lane+0], c1 = sfx[4*lane+1], c2 = sfx[4*lane+2], c3 = sfx[4*lane+3];
                int tot = c0 + c1 + c2 + c3;
                int acc = tot;
                for (int s = 1; s < 64; s <<= 1) {
                    int u = __shfl_down(acc, s);
                    if (lane + s < 64) acc += u;
                }
                int aboveG = acc - tot;
                int CS3 = aboveG;
                int CS2 = CS3 + c3;
                int CS1 = CS2 + c2;
                int CS0 = CS1 + c1;
                int CSv[4] = {CS0, CS1, CS2, CS3};
                int cv[4]  = {c0, c1, c2, c3};
#pragma unroll
                for (int j = 0; j < 4; ++j) {
                    if (CSv[j] < need && CSv[j] + cv[j] >= need) {
                        int cum = CSv[j];
                        for (int b = (4*lane+j)*16 + 15; b >= (4*lane+j)*16; --b) {
                            int h = (int)hist[b];
                            if (cum + h >= need) { sh_d = b; sh_before = cum; break; }
                            cum += h;
                        }
                    }
                }
            }
            __syncthreads();
            int d = sh_d, sb = sh_before;
            int tie = (int)hist[d];
            unsigned long long lo = ((unsigned long long)(unsigned)d) << 43;
            int total = sb + tie;

            if (total > REFINE_THR) {
                // refine with 11 more bits -> fixes ALL delta bits; M <= need + exact-iou ties
                __syncthreads();
                for (int i = t; i < 2048; i += TPC) hist[i] = 0u;
                __syncthreads();
                for (int i = t; i < C; i += TPC) {
                    unsigned long long k2 = g_cand[i];
                    if ((unsigned)(k2 >> 43) == (unsigned)d)
                        atomicAdd(&hist[(unsigned)(k2 >> 32) & 0x7FFu], 1u);
                }
                __syncthreads();
                if (t == 0) {
                    int cum = sb;
                    for (int b = 2047; b >= 0; --b) {
                        int h = (int)hist[b];
                        if (cum + h >= need) { sh_d2 = b; break; }
                        cum += h;
                    }
                }
                __syncthreads();
                lo |= ((unsigned long long)(unsigned)sh_d2) << 32;
            }

            if (t == 0) sh_cnt = 0;
            __syncthreads();
            for (int i = t; i < C; i += TPC) {
                unsigned long long k2 = g_cand[i];
                if (k2 >= lo) {
                    int s2 = atomicAdd(&sh_cnt, 1);
                    if (s2 < BLK_CAND) cbuf[s2] = k2;
                }
            }
            __syncthreads();
            M = sh_cnt < BLK_CAND ? sh_cnt : BLK_CAND;
        }

        // sorted top-needTotal via parallel rank-count (keys unique)
        for (int i = t; i < M; i += TPC) {
            unsigned long long ki = cbuf[i];
            int r = 0;
            for (int j = 0; j < M; ++j) r += (cbuf[j] > ki) ? 1 : 0;
            if (r < needTotal) lst[r] = ki;
        }
        __syncthreads();

        unsigned int kp0, kp1, kn0, kn1;
        derive_keys(kp0, kp1, kn0, kn1);
        if (t < needTotal) {
            float u = jax_uniform(kp0, kp1, (unsigned)t, 100u);
            skeys[t] = ((unsigned long long)__float_as_uint(u) << 32)
                     | (unsigned long long)(~(unsigned)t);
        }
        __syncthreads();
        if (t < needTotal) {
            unsigned long long s = skeys[t];
            int r = 0;
            for (int j = 0; j < needTotal; ++j) r += (skeys[j] > s) ? 1 : 0;
            if (r < 10) selIdx[r] = t;
        }
        __syncthreads();

        if (t < 10) {   // decode positives into LDS staging
            unsigned long long key = lst[selIdx[t]];
            unsigned int fidx = ~(unsigned int)(key & 0xFFFFFFFFull);
            int aa = fidx % A; unsigned int rest = fidx / A;
            int gg = rest % G; rest /= G;
            int ww = rest % W; rest /= W;
            int hh = rest % H; int bb = rest / H;
            s_a[t] = aa; s_g[t] = gg; s_ww[t] = ww; s_hh[t] = hh; s_bb[t] = bb;
            s_pos[t] = (bb * H + hh) * W + ww;
        }
        __syncthreads();

        // flat cooperative gather for out[0..509] (single pass, e = t)
        if (t < 510) {
            int e = t;
            float v;
            if (e < 50)       { int i = e / 5, f = e - 5 * i;
                                v = (float)((f==0)?s_bb[i]:(f==1)?s_hh[i]:(f==2)?s_ww[i]:(f==3)?s_g[i]:s_a[i]); }
            else if (e < 90)  { int u = e - 50, i = u >> 2, q = u & 3;
                                v = proposals[(size_t)(s_pos[i] * A + s_a[i]) * 4 + q]; }
            else if (e < 270) { int u = e - 90, i = u / 18, q = u - 18 * i;
                                v = cls_prob[(size_t)s_pos[i] * K + q]; }
            else if (e < 310) { int u = e - 270, i = u >> 2, q = u & 3;
                                v = gtp[s_g[i] * 4 + q]; }
            else if (e < 320) { v = (float)gtc[s_g[e - 310]]; }
            else if (e < 330) { v = (float)s_a[e - 320]; }
            else              { int u = e - 330, i = u / 18, q = u - 18 * i;
                                v = anchor_prob[(size_t)s_pos[i] * K + q]; }
            out[e] = v;
        }

        // reset device state for next replay — done by THE SAME block that read it
        __syncthreads();
        for (int i = t; i < 4096; i += TPC) g_hist[i] = 0u;
        if (t == 0) g_candCount = 0;

    } else {
        // ---------------- negatives: merge 6250 per-block top-10s (R7 verbatim) ----------------
        unsigned long long top[10];
#pragma unroll
        for (int j = 0; j < 10; ++j) top[j] = 0ull;
        for (int i = t; i < NB_P * 10; i += TPC) {
            unsigned long long key = g_negtop[i];
#pragma unroll
            for (int j = 0; j < 10; ++j) {
                if (key > top[j]) { unsigned long long tmp = top[j]; top[j] = key; key = tmp; }
            }
        }
        int lane = t & 63, wid = t >> 6;     // 8 waves
        for (int r = 0; r < 10; ++r) {
            unsigned long long w = top[0];
            for (int s = 1; s < 64; s <<= 1) {
                unsigned long long o = __shfl_xor(w, s);
                if (o > w) w = o;
            }
            if (lane == 0) wred[wid] = w;
            __syncthreads();
            unsigned long long m = wred[0];
#pragma unroll
            for (int i = 1; i < 8; ++i) { unsigned long long x = wred[i]; if (x > m) m = x; }
            if (t == 0) swin[r] = m;
            if (top[0] == m) {
#pragma unroll
                for (int j = 0; j < 9; ++j) top[j] = top[j + 1];
                top[9] = 0ull;
            }
            __syncthreads();
        }
        if (t < 10) s_npos[t] = (int)(~(unsigned int)(swin[t] & 0xFFFFFFFFull));
        __syncthreads();

        // flat gather for out[510..719] (single pass, 210 elements)
        if (t < 210) {
            int e = 510 + t;
            float v;
            if (e < 540) { int u = e - 510, i = u / 3, f = u - 3 * i; int p = s_npos[i];
                           v = (float)((f==0) ? (p / (H * W)) : (f==1) ? ((p / W) % H) : (p % W)); }
            else         { int u = e - 540, i = u / 18, q = u - 18 * i;
                           v = cls_prob[(size_t)s_npos[i] * K + q]; }
            out[e] = v;
        }
    }
}

// ---------------- launcher ----------------
extern "C" void kernel_launch(void* const* d_in, const int* in_sizes, int n_in,
                              void* d_out, int out_size, void* d_ws, size_t ws_size,
                              hipStream_t stream) {
    const float* proposals   = (const float*)d_in[0];
    const float* cls_prob    = (const float*)d_in[1];
    const float* anchor_prob = (const float*)d_in[2];
    const float* gtp         = (const float*)d_in[3];
    const int*   gtc         = (const int*)d_in[4];
    float* out = (float*)d_out;

    prod_kernel<<<NB_P, TPB, 0, stream>>>(proposals, gtp);
    cons_kernel<<<2, TPC, 0, stream>>>(proposals, cls_prob, anchor_prob, gtp, gtc, out);
}